// Round 1
// baseline (13127.104 us; speedup 1.0000x reference)
//
#include <hip/hip_runtime.h>

#define N_NODES  100000
#define N_EDGES  1600000
#define N_GRAPHS 1024
#define D        128
#define BN_EPS   1e-5f

// ---------------- CSR build ----------------

__global__ void zero_kernel(int* __restrict__ p, int n) {
    int i = blockIdx.x * blockDim.x + threadIdx.x;
    if (i < n) p[i] = 0;
}

__global__ void hist_kernel(const int* __restrict__ dst, int* __restrict__ deg) {
    int e = blockIdx.x * blockDim.x + threadIdx.x;
    if (e < N_EDGES) atomicAdd(&deg[dst[e]], 1);
}

// single-block exclusive scan of deg[0..N_NODES) -> offsets[0..N_NODES], cursor copy
__global__ __launch_bounds__(1024) void scan_kernel(const int* __restrict__ deg,
                                                    int* __restrict__ offsets,
                                                    int* __restrict__ cursor) {
    __shared__ int part[1024];
    int t = threadIdx.x;
    const int CH = (N_NODES + 1023) / 1024;  // 98
    int lo = t * CH;
    int hi = lo + CH; if (hi > N_NODES) hi = N_NODES; if (lo > N_NODES) lo = N_NODES;
    int s = 0;
    for (int i = lo; i < hi; ++i) s += deg[i];
    part[t] = s;
    __syncthreads();
    // inclusive Hillis-Steele scan
    for (int off = 1; off < 1024; off <<= 1) {
        int v = (t >= off) ? part[t - off] : 0;
        __syncthreads();
        part[t] += v;
        __syncthreads();
    }
    int run = (t == 0) ? 0 : part[t - 1];
    for (int i = lo; i < hi; ++i) {
        int d = deg[i];
        offsets[i] = run;
        cursor[i]  = run;
        run += d;
    }
    if (t == 1023) offsets[N_NODES] = run;  // == N_EDGES
}

__global__ void fill_kernel(const int* __restrict__ src, const int* __restrict__ dst,
                            int* __restrict__ cursor, int* __restrict__ csr_src) {
    int e = blockIdx.x * blockDim.x + threadIdx.x;
    if (e < N_EDGES) {
        int slot = atomicAdd(&cursor[dst[e]], 1);
        csr_src[slot] = src[e];
    }
}

// per-graph start offsets via binary search over sorted batch
__global__ void gstart_kernel(const int* __restrict__ batch, int* __restrict__ gstart) {
    int g = blockIdx.x * blockDim.x + threadIdx.x;
    if (g > N_GRAPHS) return;
    int lo = 0, hi = N_NODES;
    while (lo < hi) {
        int mid = (lo + hi) >> 1;
        if (batch[mid] < g) lo = mid + 1; else hi = mid;
    }
    gstart[g] = lo;
}

// ---------------- aggregation: h[i] = x[i] + sum_{e: dst(e)=i} x[src(e)] ----------------
// one wave per node, float2 per lane (64*2 = 128 features)
__global__ __launch_bounds__(256) void gather_kernel(const float* __restrict__ x,
                                                     const int* __restrict__ offsets,
                                                     const int* __restrict__ csr_src,
                                                     float* __restrict__ h) {
    int wave = threadIdx.x >> 6;
    int lane = threadIdx.x & 63;
    int node = blockIdx.x * 4 + wave;   // grid is exact: 25000*4 == N_NODES
    const float2* xr = (const float2*)(x + (size_t)node * D);
    float2 acc = xr[lane];
    int b = offsets[node], e_end = offsets[node + 1];
    for (int e = b; e < e_end; ++e) {
        int s = csr_src[e];
        float2 v = ((const float2*)(x + (size_t)s * D))[lane];
        acc.x += v.x; acc.y += v.y;
    }
    ((float2*)(h + (size_t)node * D))[lane] = acc;
}

// ---------------- GEMM: out = epilogue(in @ W), tile 32 rows x 128 cols ----------------
// 256 threads, 4x4 micro-tile each. W (128x128, 64KB) + A-tile (16KB) in LDS.
// In-place safe (block stages its own rows fully before writing).
__global__ __launch_bounds__(256) void gemm_kernel(
        const float* __restrict__ in, float* __restrict__ out,
        const float* __restrict__ W, const float* __restrict__ bias,
        const float* __restrict__ gamma, const float* __restrict__ beta,
        const float* __restrict__ mean, const float* __restrict__ var,
        int do_bn, int do_relu) {
    __shared__ float As[32 * 128];
    __shared__ float Bs[128 * 128];
    int t = threadIdx.x;
    int row0 = blockIdx.x * 32;   // N_NODES % 32 == 0 (3125 blocks)

#pragma unroll
    for (int i = 0; i < 4; ++i) {
        int f = t + 256 * i;            // float4 index in 32x128 tile
        int m = f >> 5, k4 = f & 31;
        float4 v = *(const float4*)(in + (size_t)(row0 + m) * D + k4 * 4);
        *(float4*)(As + m * 128 + k4 * 4) = v;
    }
#pragma unroll
    for (int i = 0; i < 16; ++i) {
        int f = t + 256 * i;            // float4 index in 128x128 W
        *(float4*)(Bs + f * 4) = *(const float4*)(W + f * 4);
    }
    __syncthreads();

    int c = t & 31, r = t >> 5;
    int n0 = c * 4, m0 = r * 4;
    float acc[4][4] = {};

#pragma unroll
    for (int k4 = 0; k4 < 32; ++k4) {
        float4 bv0 = *(const float4*)(Bs + (k4 * 4 + 0) * 128 + n0);
        float4 bv1 = *(const float4*)(Bs + (k4 * 4 + 1) * 128 + n0);
        float4 bv2 = *(const float4*)(Bs + (k4 * 4 + 2) * 128 + n0);
        float4 bv3 = *(const float4*)(Bs + (k4 * 4 + 3) * 128 + n0);
        const float* bp0 = (const float*)&bv0;
        const float* bp1 = (const float*)&bv1;
        const float* bp2 = (const float*)&bv2;
        const float* bp3 = (const float*)&bv3;
#pragma unroll
        for (int mm = 0; mm < 4; ++mm) {
            float4 av = *(const float4*)(As + (m0 + mm) * 128 + k4 * 4);
#pragma unroll
            for (int nn = 0; nn < 4; ++nn) {
                float a = acc[mm][nn];
                a = fmaf(av.x, bp0[nn], a);
                a = fmaf(av.y, bp1[nn], a);
                a = fmaf(av.z, bp2[nn], a);
                a = fmaf(av.w, bp3[nn], a);
                acc[mm][nn] = a;
            }
        }
    }

    // epilogue: z = acc*s + o  (BN folded), optional ReLU
#pragma unroll
    for (int nn = 0; nn < 4; ++nn) {
        int j = n0 + nn;
        float s, o;
        if (do_bn) {
            float inv = rsqrtf(var[j] + BN_EPS);
            s = gamma[j] * inv;
            o = (bias[j] - mean[j]) * s + beta[j];
        } else {
            s = 1.0f;
            o = bias[j];
        }
#pragma unroll
        for (int mm = 0; mm < 4; ++mm) {
            float z = fmaf(acc[mm][nn], s, o);
            if (do_relu) z = fmaxf(z, 0.0f);
            acc[mm][nn] = z;
        }
    }
#pragma unroll
    for (int mm = 0; mm < 4; ++mm) {
        *(float4*)(out + (size_t)(row0 + m0 + mm) * D + n0) =
            make_float4(acc[mm][0], acc[mm][1], acc[mm][2], acc[mm][3]);
    }
}

// ---------------- pooling: g[b] = sum of x rows in [gstart[b], gstart[b+1]) ----------------
__global__ __launch_bounds__(128) void pool_kernel(const float* __restrict__ x,
                                                   const int* __restrict__ gstart,
                                                   float* __restrict__ g) {
    int gr = blockIdx.x;
    int j  = threadIdx.x;
    float acc = 0.0f;
    int b = gstart[gr], e = gstart[gr + 1];
    for (int i = b; i < e; ++i) acc += x[(size_t)i * D + j];
    g[gr * D + j] = acc;
}

// ---------------- head: out = ReLU(g@W1+b1) @ W2 + b2 ----------------
__global__ __launch_bounds__(128) void head_kernel(const float* __restrict__ g,
                                                   const float* __restrict__ W1,
                                                   const float* __restrict__ b1,
                                                   const float* __restrict__ W2,
                                                   const float* __restrict__ b2,
                                                   float* __restrict__ out) {
    __shared__ float row[128];
    __shared__ float t1[128];
    int r = blockIdx.x, j = threadIdx.x;
    row[j] = g[r * D + j];
    __syncthreads();
    float acc = b1[j];
    for (int k = 0; k < D; ++k) acc = fmaf(row[k], W1[k * D + j], acc);
    t1[j] = fmaxf(acc, 0.0f);
    __syncthreads();
    float acc2 = b2[j];
    for (int k = 0; k < D; ++k) acc2 = fmaf(t1[k], W2[k * D + j], acc2);
    out[r * D + j] = acc2;
}

// ---------------- launcher ----------------
extern "C" void kernel_launch(void* const* d_in, const int* in_sizes, int n_in,
                              void* d_out, int out_size, void* d_ws, size_t ws_size,
                              hipStream_t stream) {
    const float* x        = (const float*)d_in[0];
    const int*   ei       = (const int*)d_in[1];
    const int*   src      = ei;
    const int*   dst      = ei + N_EDGES;
    const int*   batch    = (const int*)d_in[2];
    const float* conv_W1  = (const float*)d_in[3];
    const float* conv_b1  = (const float*)d_in[4];
    const float* bn_gamma = (const float*)d_in[5];
    const float* bn_beta  = (const float*)d_in[6];
    const float* bn_mean  = (const float*)d_in[7];
    const float* bn_var   = (const float*)d_in[8];
    const float* conv_W2  = (const float*)d_in[9];
    const float* conv_b2  = (const float*)d_in[10];
    const float* head_W1  = (const float*)d_in[11];
    const float* head_b1  = (const float*)d_in[12];
    const float* head_W2  = (const float*)d_in[13];
    const float* head_b2  = (const float*)d_in[14];
    float* out = (float*)d_out;

    char* ws = (char*)d_ws;
    size_t off = 0;
    auto alloc = [&](size_t bytes) -> void* {
        void* p = ws + off;
        off = (off + bytes + 255) & ~(size_t)255;
        return p;
    };
    float* xbuf    = (float*)alloc((size_t)N_NODES * D * sizeof(float));   // 51.2 MB
    float* hbuf    = (float*)alloc((size_t)N_NODES * D * sizeof(float));   // 51.2 MB
    int*   csr_src = (int*)alloc((size_t)N_EDGES * sizeof(int));           // 6.4 MB
    int*   offsets = (int*)alloc((size_t)(N_NODES + 1) * sizeof(int));
    int*   cursor  = (int*)alloc((size_t)N_NODES * sizeof(int));
    int*   deg     = (int*)alloc((size_t)N_NODES * sizeof(int));
    int*   gstart  = (int*)alloc((size_t)(N_GRAPHS + 1) * sizeof(int));
    float* gpool   = (float*)alloc((size_t)N_GRAPHS * D * sizeof(float));

    // CSR build (edge_index identical for all 3 layers -> build once)
    zero_kernel<<<(N_NODES + 255) / 256, 256, 0, stream>>>(deg, N_NODES);
    hist_kernel<<<(N_EDGES + 255) / 256, 256, 0, stream>>>(dst, deg);
    scan_kernel<<<1, 1024, 0, stream>>>(deg, offsets, cursor);
    fill_kernel<<<(N_EDGES + 255) / 256, 256, 0, stream>>>(src, dst, cursor, csr_src);
    gstart_kernel<<<(N_GRAPHS + 1 + 255) / 256, 256, 0, stream>>>(batch, gstart);

    const float* cur = x;
    for (int l = 0; l < 3; ++l) {
        gather_kernel<<<N_NODES / 4, 256, 0, stream>>>(cur, offsets, csr_src, hbuf);
        gemm_kernel<<<N_NODES / 32, 256, 0, stream>>>(
            hbuf, hbuf, conv_W1 + (size_t)l * D * D, conv_b1 + l * D,
            bn_gamma + l * D, bn_beta + l * D, bn_mean + l * D, bn_var + l * D, 1, 1);
        gemm_kernel<<<N_NODES / 32, 256, 0, stream>>>(
            hbuf, xbuf, conv_W2 + (size_t)l * D * D, conv_b2 + l * D,
            nullptr, nullptr, nullptr, nullptr, 0, 1);
        cur = xbuf;
    }

    pool_kernel<<<N_GRAPHS, 128, 0, stream>>>(xbuf, gstart, gpool);
    head_kernel<<<N_GRAPHS, 128, 0, stream>>>(gpool, head_W1, head_b1,
                                              head_W2, head_b2, out);
}

// Round 2
// 1388.794 us; speedup vs baseline: 9.4522x; 9.4522x over previous
//
#include <hip/hip_runtime.h>

#define N_NODES  100000
#define N_EDGES  1600000
#define N_GRAPHS 1024
#define D        128
#define BN_EPS   1e-5f

// ---------------- CSR build ----------------

__global__ void zero_kernel(int* __restrict__ p, int n) {
    int i = blockIdx.x * blockDim.x + threadIdx.x;
    if (i < n) p[i] = 0;
}

__global__ void hist_kernel(const int* __restrict__ dst, int* __restrict__ deg) {
    int e = blockIdx.x * blockDim.x + threadIdx.x;
    if (e < N_EDGES) atomicAdd(&deg[dst[e]], 1);
}

// single-block exclusive scan of deg[0..N_NODES) -> offsets[0..N_NODES], cursor copy
__global__ __launch_bounds__(1024) void scan_kernel(const int* __restrict__ deg,
                                                    int* __restrict__ offsets,
                                                    int* __restrict__ cursor) {
    __shared__ int part[1024];
    int t = threadIdx.x;
    const int CH = (N_NODES + 1023) / 1024;  // 98
    int lo = t * CH;
    int hi = lo + CH; if (hi > N_NODES) hi = N_NODES; if (lo > N_NODES) lo = N_NODES;
    int s = 0;
    for (int i = lo; i < hi; ++i) s += deg[i];
    part[t] = s;
    __syncthreads();
    for (int off = 1; off < 1024; off <<= 1) {
        int v = (t >= off) ? part[t - off] : 0;
        __syncthreads();
        part[t] += v;
        __syncthreads();
    }
    int run = (t == 0) ? 0 : part[t - 1];
    for (int i = lo; i < hi; ++i) {
        int d = deg[i];
        offsets[i] = run;
        cursor[i]  = run;
        run += d;
    }
    if (t == 1023) offsets[N_NODES] = run;  // == N_EDGES
}

__global__ void fill_kernel(const int* __restrict__ src, const int* __restrict__ dst,
                            int* __restrict__ cursor, int* __restrict__ csr_src) {
    int e = blockIdx.x * blockDim.x + threadIdx.x;
    if (e < N_EDGES) {
        int slot = atomicAdd(&cursor[dst[e]], 1);
        csr_src[slot] = src[e];
    }
}

__global__ void gstart_kernel(const int* __restrict__ batch, int* __restrict__ gstart) {
    int g = blockIdx.x * blockDim.x + threadIdx.x;
    if (g > N_GRAPHS) return;
    int lo = 0, hi = N_NODES;
    while (lo < hi) {
        int mid = (lo + hi) >> 1;
        if (batch[mid] < g) lo = mid + 1; else hi = mid;
    }
    gstart[g] = lo;
}

// ---------------- aggregation: h[i] = x[i] + sum_{e: dst(e)=i} x[src(e)] ----------------
__global__ __launch_bounds__(256) void gather_kernel(const float* __restrict__ x,
                                                     const int* __restrict__ offsets,
                                                     const int* __restrict__ csr_src,
                                                     float* __restrict__ h) {
    int wave = threadIdx.x >> 6;
    int lane = threadIdx.x & 63;
    int node = blockIdx.x * 4 + wave;   // grid exact: 25000*4 == N_NODES
    const float2* xr = (const float2*)(x + (size_t)node * D);
    float2 acc = xr[lane];
    int b = offsets[node], e_end = offsets[node + 1];
    for (int e = b; e < e_end; ++e) {
        int s = csr_src[e];
        float2 v = ((const float2*)(x + (size_t)s * D))[lane];
        acc.x += v.x; acc.y += v.y;
    }
    ((float2*)(h + (size_t)node * D))[lane] = acc;
}

// ---------------- GEMM: out = epilogue(in @ W), tile 32 rows x 128 cols ----------------
// 256 threads, 4x4 micro-tile each. All fragments are float4 VALUES (no
// address-taken locals -> no scratch spill). LDS typed as float4.
__global__ __launch_bounds__(256) void gemm_kernel(
        const float* __restrict__ in, float* __restrict__ out,
        const float* __restrict__ W, const float* __restrict__ bias,
        const float* __restrict__ gamma, const float* __restrict__ beta,
        const float* __restrict__ mean, const float* __restrict__ var,
        int do_bn, int do_relu) {
    __shared__ float4 As4[32 * 32];    // 32 rows x 128 cols  (16 KB)
    __shared__ float4 Bs4[128 * 32];   // 128 rows x 128 cols (64 KB)
    int t = threadIdx.x;
    int row0 = blockIdx.x * 32;        // N_NODES % 32 == 0 (3125 blocks)

    const float4* in4 = (const float4*)in;
    const float4* W4  = (const float4*)W;
#pragma unroll
    for (int i = 0; i < 4; ++i) {
        int f = t + 256 * i;           // float4 index in 32x128 tile
        int m = f >> 5, k4 = f & 31;
        As4[m * 32 + k4] = in4[(size_t)(row0 + m) * 32 + k4];
    }
#pragma unroll
    for (int i = 0; i < 16; ++i) {
        int f = t + 256 * i;           // float4 index in 128x128 W
        Bs4[f] = W4[f];
    }
    __syncthreads();

    int c = t & 31, r = t >> 5;        // c: col-group 0..31, r: row-group 0..7
    int n0 = c * 4, m0 = r * 4;
    float4 acc0 = {0,0,0,0}, acc1 = {0,0,0,0}, acc2 = {0,0,0,0}, acc3 = {0,0,0,0};

#pragma unroll 4
    for (int k4 = 0; k4 < 32; ++k4) {
        float4 b0 = Bs4[(k4 * 4 + 0) * 32 + c];
        float4 b1 = Bs4[(k4 * 4 + 1) * 32 + c];
        float4 b2 = Bs4[(k4 * 4 + 2) * 32 + c];
        float4 b3 = Bs4[(k4 * 4 + 3) * 32 + c];
#define GIN_MM(AV, ACC)                                                         \
        ACC.x = fmaf(AV.x, b0.x, ACC.x); ACC.x = fmaf(AV.y, b1.x, ACC.x);       \
        ACC.x = fmaf(AV.z, b2.x, ACC.x); ACC.x = fmaf(AV.w, b3.x, ACC.x);       \
        ACC.y = fmaf(AV.x, b0.y, ACC.y); ACC.y = fmaf(AV.y, b1.y, ACC.y);       \
        ACC.y = fmaf(AV.z, b2.y, ACC.y); ACC.y = fmaf(AV.w, b3.y, ACC.y);       \
        ACC.z = fmaf(AV.x, b0.z, ACC.z); ACC.z = fmaf(AV.y, b1.z, ACC.z);       \
        ACC.z = fmaf(AV.z, b2.z, ACC.z); ACC.z = fmaf(AV.w, b3.z, ACC.z);       \
        ACC.w = fmaf(AV.x, b0.w, ACC.w); ACC.w = fmaf(AV.y, b1.w, ACC.w);       \
        ACC.w = fmaf(AV.z, b2.w, ACC.w); ACC.w = fmaf(AV.w, b3.w, ACC.w);
        {
            float4 a0 = As4[(m0 + 0) * 32 + k4];
            GIN_MM(a0, acc0)
            float4 a1 = As4[(m0 + 1) * 32 + k4];
            GIN_MM(a1, acc1)
            float4 a2 = As4[(m0 + 2) * 32 + k4];
            GIN_MM(a2, acc2)
            float4 a3 = As4[(m0 + 3) * 32 + k4];
            GIN_MM(a3, acc3)
        }
#undef GIN_MM
    }

    // epilogue: z = acc*s + o (BN folded into scale/offset), optional ReLU
    float sx, sy, sz, sw, ox, oy, oz, ow;
    if (do_bn) {
        float ivx = rsqrtf(var[n0 + 0] + BN_EPS);
        float ivy = rsqrtf(var[n0 + 1] + BN_EPS);
        float ivz = rsqrtf(var[n0 + 2] + BN_EPS);
        float ivw = rsqrtf(var[n0 + 3] + BN_EPS);
        sx = gamma[n0 + 0] * ivx; sy = gamma[n0 + 1] * ivy;
        sz = gamma[n0 + 2] * ivz; sw = gamma[n0 + 3] * ivw;
        ox = (bias[n0 + 0] - mean[n0 + 0]) * sx + beta[n0 + 0];
        oy = (bias[n0 + 1] - mean[n0 + 1]) * sy + beta[n0 + 1];
        oz = (bias[n0 + 2] - mean[n0 + 2]) * sz + beta[n0 + 2];
        ow = (bias[n0 + 3] - mean[n0 + 3]) * sw + beta[n0 + 3];
    } else {
        sx = sy = sz = sw = 1.0f;
        ox = bias[n0 + 0]; oy = bias[n0 + 1]; oz = bias[n0 + 2]; ow = bias[n0 + 3];
    }

    float4* out4 = (float4*)out;
#define GIN_EPI(ACC, MM)                                                        \
    {                                                                           \
        float zx = fmaf(ACC.x, sx, ox), zy = fmaf(ACC.y, sy, oy);               \
        float zz = fmaf(ACC.z, sz, oz), zw = fmaf(ACC.w, sw, ow);               \
        if (do_relu) { zx = fmaxf(zx, 0.0f); zy = fmaxf(zy, 0.0f);              \
                       zz = fmaxf(zz, 0.0f); zw = fmaxf(zw, 0.0f); }            \
        out4[(size_t)(row0 + m0 + MM) * 32 + c] = make_float4(zx, zy, zz, zw);  \
    }
    GIN_EPI(acc0, 0)
    GIN_EPI(acc1, 1)
    GIN_EPI(acc2, 2)
    GIN_EPI(acc3, 3)
#undef GIN_EPI
}

// ---------------- pooling ----------------
__global__ __launch_bounds__(128) void pool_kernel(const float* __restrict__ x,
                                                   const int* __restrict__ gstart,
                                                   float* __restrict__ g) {
    int gr = blockIdx.x;
    int j  = threadIdx.x;
    float acc = 0.0f;
    int b = gstart[gr], e = gstart[gr + 1];
    for (int i = b; i < e; ++i) acc += x[(size_t)i * D + j];
    g[gr * D + j] = acc;
}

// ---------------- head ----------------
__global__ __launch_bounds__(128) void head_kernel(const float* __restrict__ g,
                                                   const float* __restrict__ W1,
                                                   const float* __restrict__ b1,
                                                   const float* __restrict__ W2,
                                                   const float* __restrict__ b2,
                                                   float* __restrict__ out) {
    __shared__ float row[128];
    __shared__ float t1[128];
    int r = blockIdx.x, j = threadIdx.x;
    row[j] = g[r * D + j];
    __syncthreads();
    float acc = b1[j];
    for (int k = 0; k < D; ++k) acc = fmaf(row[k], W1[k * D + j], acc);
    t1[j] = fmaxf(acc, 0.0f);
    __syncthreads();
    float acc2 = b2[j];
    for (int k = 0; k < D; ++k) acc2 = fmaf(t1[k], W2[k * D + j], acc2);
    out[r * D + j] = acc2;
}

// ---------------- launcher ----------------
extern "C" void kernel_launch(void* const* d_in, const int* in_sizes, int n_in,
                              void* d_out, int out_size, void* d_ws, size_t ws_size,
                              hipStream_t stream) {
    const float* x        = (const float*)d_in[0];
    const int*   ei       = (const int*)d_in[1];
    const int*   src      = ei;
    const int*   dst      = ei + N_EDGES;
    const int*   batch    = (const int*)d_in[2];
    const float* conv_W1  = (const float*)d_in[3];
    const float* conv_b1  = (const float*)d_in[4];
    const float* bn_gamma = (const float*)d_in[5];
    const float* bn_beta  = (const float*)d_in[6];
    const float* bn_mean  = (const float*)d_in[7];
    const float* bn_var   = (const float*)d_in[8];
    const float* conv_W2  = (const float*)d_in[9];
    const float* conv_b2  = (const float*)d_in[10];
    const float* head_W1  = (const float*)d_in[11];
    const float* head_b1  = (const float*)d_in[12];
    const float* head_W2  = (const float*)d_in[13];
    const float* head_b2  = (const float*)d_in[14];
    float* out = (float*)d_out;

    char* ws = (char*)d_ws;
    size_t off = 0;
    auto alloc = [&](size_t bytes) -> void* {
        void* p = ws + off;
        off = (off + bytes + 255) & ~(size_t)255;
        return p;
    };
    float* xbuf    = (float*)alloc((size_t)N_NODES * D * sizeof(float));
    float* hbuf    = (float*)alloc((size_t)N_NODES * D * sizeof(float));
    int*   csr_src = (int*)alloc((size_t)N_EDGES * sizeof(int));
    int*   offsets = (int*)alloc((size_t)(N_NODES + 1) * sizeof(int));
    int*   cursor  = (int*)alloc((size_t)N_NODES * sizeof(int));
    int*   deg     = (int*)alloc((size_t)N_NODES * sizeof(int));
    int*   gstart  = (int*)alloc((size_t)(N_GRAPHS + 1) * sizeof(int));
    float* gpool   = (float*)alloc((size_t)N_GRAPHS * D * sizeof(float));

    zero_kernel<<<(N_NODES + 255) / 256, 256, 0, stream>>>(deg, N_NODES);
    hist_kernel<<<(N_EDGES + 255) / 256, 256, 0, stream>>>(dst, deg);
    scan_kernel<<<1, 1024, 0, stream>>>(deg, offsets, cursor);
    fill_kernel<<<(N_EDGES + 255) / 256, 256, 0, stream>>>(src, dst, cursor, csr_src);
    gstart_kernel<<<(N_GRAPHS + 1 + 255) / 256, 256, 0, stream>>>(batch, gstart);

    const float* cur = x;
    for (int l = 0; l < 3; ++l) {
        gather_kernel<<<N_NODES / 4, 256, 0, stream>>>(cur, offsets, csr_src, hbuf);
        gemm_kernel<<<N_NODES / 32, 256, 0, stream>>>(
            hbuf, hbuf, conv_W1 + (size_t)l * D * D, conv_b1 + l * D,
            bn_gamma + l * D, bn_beta + l * D, bn_mean + l * D, bn_var + l * D, 1, 1);
        gemm_kernel<<<N_NODES / 32, 256, 0, stream>>>(
            hbuf, xbuf, conv_W2 + (size_t)l * D * D, conv_b2 + l * D,
            nullptr, nullptr, nullptr, nullptr, 0, 1);
        cur = xbuf;
    }

    pool_kernel<<<N_GRAPHS, 128, 0, stream>>>(xbuf, gstart, gpool);
    head_kernel<<<N_GRAPHS, 128, 0, stream>>>(gpool, head_W1, head_b1,
                                              head_W2, head_b2, out);
}

// Round 3
// 1159.274 us; speedup vs baseline: 11.3236x; 1.1980x over previous
//
#include <hip/hip_runtime.h>

#define N_NODES  100000
#define N_EDGES  1600000
#define N_GRAPHS 1024
#define D        128
#define BN_EPS   1e-5f

#define SCAN_BLOCK 1024
#define SCAN_NBLK  ((N_NODES + SCAN_BLOCK - 1) / SCAN_BLOCK)   // 98

// ---------------- CSR build ----------------

__global__ void zero_kernel(int* __restrict__ p, int n) {
    int i = blockIdx.x * blockDim.x + threadIdx.x;
    if (i < n) p[i] = 0;
}

__global__ void hist_kernel(const int* __restrict__ dst, int* __restrict__ deg) {
    int e = blockIdx.x * blockDim.x + threadIdx.x;
    if (e < N_EDGES) atomicAdd(&deg[dst[e]], 1);
}

// phase 1: per-block sums of deg
__global__ __launch_bounds__(1024) void scan_phase1(const int* __restrict__ deg,
                                                    int* __restrict__ blocksum) {
    __shared__ int red[16];
    int t = threadIdx.x;
    int i = blockIdx.x * SCAN_BLOCK + t;
    int v = (i < N_NODES) ? deg[i] : 0;
#pragma unroll
    for (int off = 32; off > 0; off >>= 1) v += __shfl_down(v, off, 64);
    if ((t & 63) == 0) red[t >> 6] = v;
    __syncthreads();
    if (t == 0) {
        int s = 0;
#pragma unroll
        for (int w = 0; w < 16; ++w) s += red[w];
        blocksum[blockIdx.x] = s;
    }
}

// phase 2: exclusive scan of the 98 block sums (one small block)
__global__ __launch_bounds__(128) void scan_phase2(const int* __restrict__ blocksum,
                                                   int* __restrict__ blockoff,
                                                   int* __restrict__ offsets) {
    __shared__ int part[128];
    int t = threadIdx.x;
    int v = (t < SCAN_NBLK) ? blocksum[t] : 0;
    part[t] = v;
    __syncthreads();
    for (int off = 1; off < 128; off <<= 1) {
        int u = (t >= off) ? part[t - off] : 0;
        __syncthreads();
        part[t] += u;
        __syncthreads();
    }
    if (t < SCAN_NBLK) blockoff[t] = part[t] - v;   // exclusive
    if (t == 0) offsets[N_NODES] = N_EDGES;
}

// phase 3: per-chunk exclusive scan + block offset -> offsets, cursor
__global__ __launch_bounds__(1024) void scan_phase3(const int* __restrict__ deg,
                                                    const int* __restrict__ blockoff,
                                                    int* __restrict__ offsets,
                                                    int* __restrict__ cursor) {
    __shared__ int part[1024];
    int t = threadIdx.x;
    int i = blockIdx.x * SCAN_BLOCK + t;
    int v = (i < N_NODES) ? deg[i] : 0;
    part[t] = v;
    __syncthreads();
    for (int off = 1; off < 1024; off <<= 1) {
        int u = (t >= off) ? part[t - off] : 0;
        __syncthreads();
        part[t] += u;
        __syncthreads();
    }
    if (i < N_NODES) {
        int excl = blockoff[blockIdx.x] + part[t] - v;
        offsets[i] = excl;
        cursor[i]  = excl;
    }
}

__global__ void fill_kernel(const int* __restrict__ src, const int* __restrict__ dst,
                            int* __restrict__ cursor, int* __restrict__ csr_src) {
    int e = blockIdx.x * blockDim.x + threadIdx.x;
    if (e < N_EDGES) {
        int slot = atomicAdd(&cursor[dst[e]], 1);
        csr_src[slot] = src[e];
    }
}

__global__ void gstart_kernel(const int* __restrict__ batch, int* __restrict__ gstart) {
    int g = blockIdx.x * blockDim.x + threadIdx.x;
    if (g > N_GRAPHS) return;
    int lo = 0, hi = N_NODES;
    while (lo < hi) {
        int mid = (lo + hi) >> 1;
        if (batch[mid] < g) lo = mid + 1; else hi = mid;
    }
    gstart[g] = lo;
}

// ---------------- aggregation: h[i] = x[i] + sum_{e: dst(e)=i} x[src(e)] ----------------
__global__ __launch_bounds__(256) void gather_kernel(const float* __restrict__ x,
                                                     const int* __restrict__ offsets,
                                                     const int* __restrict__ csr_src,
                                                     float* __restrict__ h) {
    int wave = threadIdx.x >> 6;
    int lane = threadIdx.x & 63;
    int node = blockIdx.x * 4 + wave;   // grid exact: 25000*4 == N_NODES
    const float2* xr = (const float2*)(x + (size_t)node * D);
    float2 acc = xr[lane];
    int b = offsets[node], e_end = offsets[node + 1];
    for (int e = b; e < e_end; ++e) {
        int s = csr_src[e];
        float2 v = ((const float2*)(x + (size_t)s * D))[lane];
        acc.x += v.x; acc.y += v.y;
    }
    ((float2*)(h + (size_t)node * D))[lane] = acc;
}

// ---------------- GEMM: out = epilogue(in @ W), tile 32 rows x 128 cols ----------------
__global__ __launch_bounds__(256) void gemm_kernel(
        const float* __restrict__ in, float* __restrict__ out,
        const float* __restrict__ W, const float* __restrict__ bias,
        const float* __restrict__ gamma, const float* __restrict__ beta,
        const float* __restrict__ mean, const float* __restrict__ var,
        int do_bn, int do_relu) {
    __shared__ float4 As4[32 * 32];    // 32 rows x 128 cols  (16 KB)
    __shared__ float4 Bs4[128 * 32];   // 128 rows x 128 cols (64 KB)
    int t = threadIdx.x;
    int row0 = blockIdx.x * 32;        // N_NODES % 32 == 0 (3125 blocks)

    const float4* in4 = (const float4*)in;
    const float4* W4  = (const float4*)W;
#pragma unroll
    for (int i = 0; i < 4; ++i) {
        int f = t + 256 * i;
        int m = f >> 5, k4 = f & 31;
        As4[m * 32 + k4] = in4[(size_t)(row0 + m) * 32 + k4];
    }
#pragma unroll
    for (int i = 0; i < 16; ++i) {
        int f = t + 256 * i;
        Bs4[f] = W4[f];
    }
    __syncthreads();

    int c = t & 31, r = t >> 5;
    int n0 = c * 4, m0 = r * 4;
    float4 acc0 = {0,0,0,0}, acc1 = {0,0,0,0}, acc2 = {0,0,0,0}, acc3 = {0,0,0,0};

#pragma unroll 4
    for (int k4 = 0; k4 < 32; ++k4) {
        float4 b0 = Bs4[(k4 * 4 + 0) * 32 + c];
        float4 b1 = Bs4[(k4 * 4 + 1) * 32 + c];
        float4 b2 = Bs4[(k4 * 4 + 2) * 32 + c];
        float4 b3 = Bs4[(k4 * 4 + 3) * 32 + c];
#define GIN_MM(AV, ACC)                                                         \
        ACC.x = fmaf(AV.x, b0.x, ACC.x); ACC.x = fmaf(AV.y, b1.x, ACC.x);       \
        ACC.x = fmaf(AV.z, b2.x, ACC.x); ACC.x = fmaf(AV.w, b3.x, ACC.x);       \
        ACC.y = fmaf(AV.x, b0.y, ACC.y); ACC.y = fmaf(AV.y, b1.y, ACC.y);       \
        ACC.y = fmaf(AV.z, b2.y, ACC.y); ACC.y = fmaf(AV.w, b3.y, ACC.y);       \
        ACC.z = fmaf(AV.x, b0.z, ACC.z); ACC.z = fmaf(AV.y, b1.z, ACC.z);       \
        ACC.z = fmaf(AV.z, b2.z, ACC.z); ACC.z = fmaf(AV.w, b3.z, ACC.z);       \
        ACC.w = fmaf(AV.x, b0.w, ACC.w); ACC.w = fmaf(AV.y, b1.w, ACC.w);       \
        ACC.w = fmaf(AV.z, b2.w, ACC.w); ACC.w = fmaf(AV.w, b3.w, ACC.w);
        {
            float4 a0 = As4[(m0 + 0) * 32 + k4];
            GIN_MM(a0, acc0)
            float4 a1 = As4[(m0 + 1) * 32 + k4];
            GIN_MM(a1, acc1)
            float4 a2 = As4[(m0 + 2) * 32 + k4];
            GIN_MM(a2, acc2)
            float4 a3 = As4[(m0 + 3) * 32 + k4];
            GIN_MM(a3, acc3)
        }
#undef GIN_MM
    }

    float sx, sy, sz, sw, ox, oy, oz, ow;
    if (do_bn) {
        float ivx = rsqrtf(var[n0 + 0] + BN_EPS);
        float ivy = rsqrtf(var[n0 + 1] + BN_EPS);
        float ivz = rsqrtf(var[n0 + 2] + BN_EPS);
        float ivw = rsqrtf(var[n0 + 3] + BN_EPS);
        sx = gamma[n0 + 0] * ivx; sy = gamma[n0 + 1] * ivy;
        sz = gamma[n0 + 2] * ivz; sw = gamma[n0 + 3] * ivw;
        ox = (bias[n0 + 0] - mean[n0 + 0]) * sx + beta[n0 + 0];
        oy = (bias[n0 + 1] - mean[n0 + 1]) * sy + beta[n0 + 1];
        oz = (bias[n0 + 2] - mean[n0 + 2]) * sz + beta[n0 + 2];
        ow = (bias[n0 + 3] - mean[n0 + 3]) * sw + beta[n0 + 3];
    } else {
        sx = sy = sz = sw = 1.0f;
        ox = bias[n0 + 0]; oy = bias[n0 + 1]; oz = bias[n0 + 2]; ow = bias[n0 + 3];
    }

    float4* out4 = (float4*)out;
#define GIN_EPI(ACC, MM)                                                        \
    {                                                                           \
        float zx = fmaf(ACC.x, sx, ox), zy = fmaf(ACC.y, sy, oy);               \
        float zz = fmaf(ACC.z, sz, oz), zw = fmaf(ACC.w, sw, ow);               \
        if (do_relu) { zx = fmaxf(zx, 0.0f); zy = fmaxf(zy, 0.0f);              \
                       zz = fmaxf(zz, 0.0f); zw = fmaxf(zw, 0.0f); }            \
        out4[(size_t)(row0 + m0 + MM) * 32 + c] = make_float4(zx, zy, zz, zw);  \
    }
    GIN_EPI(acc0, 0)
    GIN_EPI(acc1, 1)
    GIN_EPI(acc2, 2)
    GIN_EPI(acc3, 3)
#undef GIN_EPI
}

// ---------------- pooling ----------------
__global__ __launch_bounds__(128) void pool_kernel(const float* __restrict__ x,
                                                   const int* __restrict__ gstart,
                                                   float* __restrict__ g) {
    int gr = blockIdx.x;
    int j  = threadIdx.x;
    float acc = 0.0f;
    int b = gstart[gr], e = gstart[gr + 1];
    for (int i = b; i < e; ++i) acc += x[(size_t)i * D + j];
    g[gr * D + j] = acc;
}

// ---------------- head ----------------
__global__ __launch_bounds__(128) void head_kernel(const float* __restrict__ g,
                                                   const float* __restrict__ W1,
                                                   const float* __restrict__ b1,
                                                   const float* __restrict__ W2,
                                                   const float* __restrict__ b2,
                                                   float* __restrict__ out) {
    __shared__ float row[128];
    __shared__ float t1[128];
    int r = blockIdx.x, j = threadIdx.x;
    row[j] = g[r * D + j];
    __syncthreads();
    float acc = b1[j];
    for (int k = 0; k < D; ++k) acc = fmaf(row[k], W1[k * D + j], acc);
    t1[j] = fmaxf(acc, 0.0f);
    __syncthreads();
    float acc2 = b2[j];
    for (int k = 0; k < D; ++k) acc2 = fmaf(t1[k], W2[k * D + j], acc2);
    out[r * D + j] = acc2;
}

// ---------------- launcher ----------------
extern "C" void kernel_launch(void* const* d_in, const int* in_sizes, int n_in,
                              void* d_out, int out_size, void* d_ws, size_t ws_size,
                              hipStream_t stream) {
    const float* x        = (const float*)d_in[0];
    const int*   ei       = (const int*)d_in[1];
    const int*   src      = ei;
    const int*   dst      = ei + N_EDGES;
    const int*   batch    = (const int*)d_in[2];
    const float* conv_W1  = (const float*)d_in[3];
    const float* conv_b1  = (const float*)d_in[4];
    const float* bn_gamma = (const float*)d_in[5];
    const float* bn_beta  = (const float*)d_in[6];
    const float* bn_mean  = (const float*)d_in[7];
    const float* bn_var   = (const float*)d_in[8];
    const float* conv_W2  = (const float*)d_in[9];
    const float* conv_b2  = (const float*)d_in[10];
    const float* head_W1  = (const float*)d_in[11];
    const float* head_b1  = (const float*)d_in[12];
    const float* head_W2  = (const float*)d_in[13];
    const float* head_b2  = (const float*)d_in[14];
    float* out = (float*)d_out;

    char* ws = (char*)d_ws;
    size_t off = 0;
    auto alloc = [&](size_t bytes) -> void* {
        void* p = ws + off;
        off = (off + bytes + 255) & ~(size_t)255;
        return p;
    };
    float* xbuf     = (float*)alloc((size_t)N_NODES * D * sizeof(float));
    float* hbuf     = (float*)alloc((size_t)N_NODES * D * sizeof(float));
    int*   csr_src  = (int*)alloc((size_t)N_EDGES * sizeof(int));
    int*   offsets  = (int*)alloc((size_t)(N_NODES + 1) * sizeof(int));
    int*   cursor   = (int*)alloc((size_t)N_NODES * sizeof(int));
    int*   deg      = (int*)alloc((size_t)N_NODES * sizeof(int));
    int*   blocksum = (int*)alloc((size_t)SCAN_NBLK * sizeof(int));
    int*   blockoff = (int*)alloc((size_t)SCAN_NBLK * sizeof(int));
    int*   gstart   = (int*)alloc((size_t)(N_GRAPHS + 1) * sizeof(int));
    float* gpool    = (float*)alloc((size_t)N_GRAPHS * D * sizeof(float));

    zero_kernel<<<(N_NODES + 255) / 256, 256, 0, stream>>>(deg, N_NODES);
    hist_kernel<<<(N_EDGES + 255) / 256, 256, 0, stream>>>(dst, deg);
    scan_phase1<<<SCAN_NBLK, 1024, 0, stream>>>(deg, blocksum);
    scan_phase2<<<1, 128, 0, stream>>>(blocksum, blockoff, offsets);
    scan_phase3<<<SCAN_NBLK, 1024, 0, stream>>>(deg, blockoff, offsets, cursor);
    fill_kernel<<<(N_EDGES + 255) / 256, 256, 0, stream>>>(src, dst, cursor, csr_src);
    gstart_kernel<<<(N_GRAPHS + 1 + 255) / 256, 256, 0, stream>>>(batch, gstart);

    const float* cur = x;
    for (int l = 0; l < 3; ++l) {
        gather_kernel<<<N_NODES / 4, 256, 0, stream>>>(cur, offsets, csr_src, hbuf);
        gemm_kernel<<<N_NODES / 32, 256, 0, stream>>>(
            hbuf, hbuf, conv_W1 + (size_t)l * D * D, conv_b1 + l * D,
            bn_gamma + l * D, bn_beta + l * D, bn_mean + l * D, bn_var + l * D, 1, 1);
        gemm_kernel<<<N_NODES / 32, 256, 0, stream>>>(
            hbuf, xbuf, conv_W2 + (size_t)l * D * D, conv_b2 + l * D,
            nullptr, nullptr, nullptr, nullptr, 0, 1);
        cur = xbuf;
    }

    pool_kernel<<<N_GRAPHS, 128, 0, stream>>>(xbuf, gstart, gpool);
    head_kernel<<<N_GRAPHS, 128, 0, stream>>>(gpool, head_W1, head_b1,
                                              head_W2, head_b2, out);
}

// Round 4
// 665.707 us; speedup vs baseline: 19.7190x; 1.7414x over previous
//
#include <hip/hip_runtime.h>

#define N_NODES  100000
#define N_EDGES  1600000
#define N_GRAPHS 1024
#define D        128
#define BN_EPS   1e-5f

#define SCAN_BLOCK 1024
#define SCAN_NBLK  ((N_NODES + SCAN_BLOCK - 1) / SCAN_BLOCK)   // 98

typedef short bf16x8 __attribute__((ext_vector_type(8)));
typedef float f32x4  __attribute__((ext_vector_type(4)));

__device__ __forceinline__ ushort f2bf(float f) {        // RNE fp32->bf16
    unsigned int b = __float_as_uint(f);
    return (ushort)((b + 0x7fffu + ((b >> 16) & 1u)) >> 16);
}
__device__ __forceinline__ float bflo(unsigned int u) { return __uint_as_float(u << 16); }
__device__ __forceinline__ float bfhi(unsigned int u) { return __uint_as_float(u & 0xffff0000u); }
__device__ __forceinline__ unsigned int packbf(float x, float y) {
    return (unsigned int)f2bf(x) | ((unsigned int)f2bf(y) << 16);
}

// ---------------- CSR build ----------------

__global__ void zero_kernel(int* __restrict__ p, int n) {
    int i = blockIdx.x * blockDim.x + threadIdx.x;
    if (i < n) p[i] = 0;
}

__global__ void hist_kernel(const int* __restrict__ dst, int* __restrict__ deg) {
    int e = blockIdx.x * blockDim.x + threadIdx.x;
    if (e < N_EDGES) atomicAdd(&deg[dst[e]], 1);
}

__global__ __launch_bounds__(1024) void scan_phase1(const int* __restrict__ deg,
                                                    int* __restrict__ blocksum) {
    __shared__ int red[16];
    int t = threadIdx.x;
    int i = blockIdx.x * SCAN_BLOCK + t;
    int v = (i < N_NODES) ? deg[i] : 0;
#pragma unroll
    for (int off = 32; off > 0; off >>= 1) v += __shfl_down(v, off, 64);
    if ((t & 63) == 0) red[t >> 6] = v;
    __syncthreads();
    if (t == 0) {
        int s = 0;
#pragma unroll
        for (int w = 0; w < 16; ++w) s += red[w];
        blocksum[blockIdx.x] = s;
    }
}

__global__ __launch_bounds__(128) void scan_phase2(const int* __restrict__ blocksum,
                                                   int* __restrict__ blockoff,
                                                   int* __restrict__ offsets) {
    __shared__ int part[128];
    int t = threadIdx.x;
    int v = (t < SCAN_NBLK) ? blocksum[t] : 0;
    part[t] = v;
    __syncthreads();
    for (int off = 1; off < 128; off <<= 1) {
        int u = (t >= off) ? part[t - off] : 0;
        __syncthreads();
        part[t] += u;
        __syncthreads();
    }
    if (t < SCAN_NBLK) blockoff[t] = part[t] - v;
    if (t == 0) offsets[N_NODES] = N_EDGES;
}

__global__ __launch_bounds__(1024) void scan_phase3(const int* __restrict__ deg,
                                                    const int* __restrict__ blockoff,
                                                    int* __restrict__ offsets,
                                                    int* __restrict__ cursor) {
    __shared__ int part[1024];
    int t = threadIdx.x;
    int i = blockIdx.x * SCAN_BLOCK + t;
    int v = (i < N_NODES) ? deg[i] : 0;
    part[t] = v;
    __syncthreads();
    for (int off = 1; off < 1024; off <<= 1) {
        int u = (t >= off) ? part[t - off] : 0;
        __syncthreads();
        part[t] += u;
        __syncthreads();
    }
    if (i < N_NODES) {
        int excl = blockoff[blockIdx.x] + part[t] - v;
        offsets[i] = excl;
        cursor[i]  = excl;
    }
}

__global__ void fill_kernel(const int* __restrict__ src, const int* __restrict__ dst,
                            int* __restrict__ cursor, int* __restrict__ csr_src) {
    int e = blockIdx.x * blockDim.x + threadIdx.x;
    if (e < N_EDGES) {
        int slot = atomicAdd(&cursor[dst[e]], 1);
        csr_src[slot] = src[e];
    }
}

__global__ void gstart_kernel(const int* __restrict__ batch, int* __restrict__ gstart) {
    int g = blockIdx.x * blockDim.x + threadIdx.x;
    if (g > N_GRAPHS) return;
    int lo = 0, hi = N_NODES;
    while (lo < hi) {
        int mid = (lo + hi) >> 1;
        if (batch[mid] < g) lo = mid + 1; else hi = mid;
    }
    gstart[g] = lo;
}

// ---------------- precompute: x -> bf16, W -> bf16 transposed, BN folds ----------------

__global__ __launch_bounds__(256) void cvt_x_kernel(const float* __restrict__ x,
                                                    ushort* __restrict__ xb) {
    size_t i = ((size_t)blockIdx.x * 256 + threadIdx.x) * 8;   // 6250 blocks exact
    float4 v0 = *(const float4*)(x + i);
    float4 v1 = *(const float4*)(x + i + 4);
    uint4 o;
    o.x = packbf(v0.x, v0.y); o.y = packbf(v0.z, v0.w);
    o.z = packbf(v1.x, v1.y); o.w = packbf(v1.z, v1.w);
    *(uint4*)(xb + i) = o;
}

// Wt[i][n][k] = bf16(W_i[k][n]); i in 0..5 = (layer, gemm1/2)
__global__ __launch_bounds__(128) void prep_w_kernel(const float* __restrict__ W1,
                                                     const float* __restrict__ W2,
                                                     ushort* __restrict__ Wt) {
    int i = blockIdx.y, k = blockIdx.x, n = threadIdx.x, l = i >> 1;
    const float* W = (i & 1) ? (W2 + (size_t)l * D * D) : (W1 + (size_t)l * D * D);
    Wt[(size_t)i * D * D + n * D + k] = f2bf(W[k * D + n]);
}

// folds[i][0][j]=scale, folds[i][1][j]=offset
__global__ __launch_bounds__(128) void prep_fold_kernel(
        const float* __restrict__ b1, const float* __restrict__ gamma,
        const float* __restrict__ beta, const float* __restrict__ mean,
        const float* __restrict__ var, const float* __restrict__ b2,
        float* __restrict__ folds) {
    int i = blockIdx.x, j = threadIdx.x, l = i >> 1;
    float s, o;
    if ((i & 1) == 0) {
        float sv = gamma[l * D + j] * rsqrtf(var[l * D + j] + BN_EPS);
        s = sv;
        o = (b1[l * D + j] - mean[l * D + j]) * sv + beta[l * D + j];
    } else {
        s = 1.0f;
        o = b2[l * D + j];
    }
    folds[(size_t)i * 2 * D + j]     = s;
    folds[(size_t)i * 2 * D + D + j] = o;
}

// ---------------- aggregation (bf16 rows, fp32 accumulate) ----------------
__global__ __launch_bounds__(256) void gather_bf16(const ushort* __restrict__ xb,
                                                   const int* __restrict__ offsets,
                                                   const int* __restrict__ csr_src,
                                                   ushort* __restrict__ hb) {
    int wv = threadIdx.x >> 6, lane = threadIdx.x & 63;
    int node = blockIdx.x * 4 + wv;           // 25000*4 == N_NODES
    const unsigned int* base = (const unsigned int*)xb;
    unsigned int u = base[(size_t)node * 64 + lane];
    float ax = bflo(u), ay = bfhi(u);
    int b = offsets[node], e = offsets[node + 1];
    int i = b;
    for (; i + 3 < e; i += 4) {               // 4 outstanding row loads
        int s0 = csr_src[i], s1 = csr_src[i + 1], s2 = csr_src[i + 2], s3 = csr_src[i + 3];
        unsigned int v0 = base[(size_t)s0 * 64 + lane];
        unsigned int v1 = base[(size_t)s1 * 64 + lane];
        unsigned int v2 = base[(size_t)s2 * 64 + lane];
        unsigned int v3 = base[(size_t)s3 * 64 + lane];
        ax += bflo(v0) + bflo(v1) + bflo(v2) + bflo(v3);
        ay += bfhi(v0) + bfhi(v1) + bfhi(v2) + bfhi(v3);
    }
    for (; i < e; ++i) {
        unsigned int v = base[(size_t)csr_src[i] * 64 + lane];
        ax += bflo(v); ay += bfhi(v);
    }
    ((unsigned int*)hb)[(size_t)node * 64 + lane] = packbf(ax, ay);
}

// ---------------- MFMA GEMM: out = relu(in @ W * s + o), bf16 in/out ----------------
// 64 rows x 128 cols per block, 256 thr (4 waves), wave = 16 rows x 128 cols.
// LDS: As 64x(128+8) bf16, Bs 128x(128+8) bf16 (Wt pre-transposed [n][k]),
// Cs 64x140 bf16 (stride 280B: quads hit banks {0,24,16,8} -> conflict-free).
__global__ __launch_bounds__(256) void gemm_mfma(const ushort* __restrict__ in,
                                                 ushort* __restrict__ out,
                                                 const ushort* __restrict__ Wt,
                                                 const float* __restrict__ fold) {
    __shared__ ushort As[64 * 136];
    __shared__ ushort Bs[128 * 136];
    __shared__ ushort Cs[64 * 140];
    int t = threadIdx.x;
    int row0 = blockIdx.x * 64;               // 1563 blocks, last partial (32 rows)

#pragma unroll
    for (int i = 0; i < 4; ++i) {             // stage A (reads may run past N into padded ws)
        int f = t + 256 * i; int m = f >> 4, g = f & 15;
        *(float4*)(As + m * 136 + g * 8) = *(const float4*)(in + (size_t)(row0 + m) * D + g * 8);
    }
#pragma unroll
    for (int i = 0; i < 8; ++i) {             // stage B
        int f = t + 256 * i; int n = f >> 4, g = f & 15;
        *(float4*)(Bs + n * 136 + g * 8) = *(const float4*)(Wt + (size_t)n * D + g * 8);
    }
    __syncthreads();

    int lane = t & 63, wv = t >> 6;
    int quad = lane >> 4, mr = lane & 15;
    int mbase = wv * 16;
    const ushort* ap = As + (mbase + mr) * 136 + quad * 8;
    bf16x8 a0 = *(const bf16x8*)(ap);
    bf16x8 a1 = *(const bf16x8*)(ap + 32);
    bf16x8 a2 = *(const bf16x8*)(ap + 64);
    bf16x8 a3 = *(const bf16x8*)(ap + 96);

#pragma unroll
    for (int nt = 0; nt < 8; ++nt) {
        const ushort* bq = Bs + (nt * 16 + mr) * 136 + quad * 8;
        bf16x8 b0 = *(const bf16x8*)(bq);
        bf16x8 b1 = *(const bf16x8*)(bq + 32);
        bf16x8 b2 = *(const bf16x8*)(bq + 64);
        bf16x8 b3 = *(const bf16x8*)(bq + 96);
        f32x4 acc = {0.f, 0.f, 0.f, 0.f};
        acc = __builtin_amdgcn_mfma_f32_16x16x32_bf16(a0, b0, acc, 0, 0, 0);
        acc = __builtin_amdgcn_mfma_f32_16x16x32_bf16(a1, b1, acc, 0, 0, 0);
        acc = __builtin_amdgcn_mfma_f32_16x16x32_bf16(a2, b2, acc, 0, 0, 0);
        acc = __builtin_amdgcn_mfma_f32_16x16x32_bf16(a3, b3, acc, 0, 0, 0);
        int j = nt * 16 + mr;                 // C/D: col=lane&15, row=quad*4+reg (m89)
        float s = fold[j], o = fold[D + j];
#pragma unroll
        for (int r = 0; r < 4; ++r) {
            float z = fmaf(acc[r], s, o);
            z = fmaxf(z, 0.0f);
            Cs[(mbase + quad * 4 + r) * 140 + j] = f2bf(z);
        }
    }
    __syncthreads();

#pragma unroll
    for (int i = 0; i < 8; ++i) {             // coalesced copy-out, float2 = 4 bf16
        int f = t + 256 * i; int lr = f >> 5, g = f & 31;
        if (row0 + lr < N_NODES)
            *(float2*)(out + (size_t)(row0 + lr) * D + g * 4) =
                *(const float2*)(Cs + lr * 140 + g * 4);
    }
}

// ---------------- pooling (bf16 in, fp32 out) ----------------
__global__ __launch_bounds__(128) void pool_kernel(const ushort* __restrict__ xb,
                                                   const int* __restrict__ gstart,
                                                   float* __restrict__ g) {
    int gr = blockIdx.x, j = threadIdx.x;
    float acc = 0.0f;
    int b = gstart[gr], e = gstart[gr + 1];
    for (int i = b; i < e; ++i)
        acc += __uint_as_float(((unsigned int)xb[(size_t)i * D + j]) << 16);
    g[gr * D + j] = acc;
}

// ---------------- head (fp32) ----------------
__global__ __launch_bounds__(128) void head_kernel(const float* __restrict__ g,
                                                   const float* __restrict__ W1,
                                                   const float* __restrict__ b1,
                                                   const float* __restrict__ W2,
                                                   const float* __restrict__ b2,
                                                   float* __restrict__ out) {
    __shared__ float row[128];
    __shared__ float t1[128];
    int r = blockIdx.x, j = threadIdx.x;
    row[j] = g[r * D + j];
    __syncthreads();
    float acc = b1[j];
    for (int k = 0; k < D; ++k) acc = fmaf(row[k], W1[k * D + j], acc);
    t1[j] = fmaxf(acc, 0.0f);
    __syncthreads();
    float acc2 = b2[j];
    for (int k = 0; k < D; ++k) acc2 = fmaf(t1[k], W2[k * D + j], acc2);
    out[r * D + j] = acc2;
}

// ---------------- launcher ----------------
extern "C" void kernel_launch(void* const* d_in, const int* in_sizes, int n_in,
                              void* d_out, int out_size, void* d_ws, size_t ws_size,
                              hipStream_t stream) {
    const float* x        = (const float*)d_in[0];
    const int*   ei       = (const int*)d_in[1];
    const int*   src      = ei;
    const int*   dst      = ei + N_EDGES;
    const int*   batch    = (const int*)d_in[2];
    const float* conv_W1  = (const float*)d_in[3];
    const float* conv_b1  = (const float*)d_in[4];
    const float* bn_gamma = (const float*)d_in[5];
    const float* bn_beta  = (const float*)d_in[6];
    const float* bn_mean  = (const float*)d_in[7];
    const float* bn_var   = (const float*)d_in[8];
    const float* conv_W2  = (const float*)d_in[9];
    const float* conv_b2  = (const float*)d_in[10];
    const float* head_W1  = (const float*)d_in[11];
    const float* head_b1  = (const float*)d_in[12];
    const float* head_W2  = (const float*)d_in[13];
    const float* head_b2  = (const float*)d_in[14];
    float* out = (float*)d_out;

    char* ws = (char*)d_ws;
    size_t off = 0;
    auto alloc = [&](size_t bytes) -> void* {
        void* p = ws + off;
        off = (off + bytes + 255) & ~(size_t)255;
        return p;
    };
    const size_t NODE_BUF = (size_t)(N_NODES + 64) * D * sizeof(ushort);  // +64 rows pad
    ushort* buf0    = (ushort*)alloc(NODE_BUF);
    ushort* buf1    = (ushort*)alloc(NODE_BUF);
    ushort* buf2    = (ushort*)alloc(NODE_BUF);
    ushort* Wt      = (ushort*)alloc((size_t)6 * D * D * sizeof(ushort));
    float*  folds   = (float*)alloc((size_t)6 * 2 * D * sizeof(float));
    int*   csr_src  = (int*)alloc((size_t)N_EDGES * sizeof(int));
    int*   offsets  = (int*)alloc((size_t)(N_NODES + 1) * sizeof(int));
    int*   cursor   = (int*)alloc((size_t)N_NODES * sizeof(int));
    int*   deg      = (int*)alloc((size_t)N_NODES * sizeof(int));
    int*   blocksum = (int*)alloc((size_t)SCAN_NBLK * sizeof(int));
    int*   blockoff = (int*)alloc((size_t)SCAN_NBLK * sizeof(int));
    int*   gstart   = (int*)alloc((size_t)(N_GRAPHS + 1) * sizeof(int));
    float* gpool    = (float*)alloc((size_t)N_GRAPHS * D * sizeof(float));

    // CSR + pool ranges + precompute (independent chains)
    zero_kernel<<<(N_NODES + 255) / 256, 256, 0, stream>>>(deg, N_NODES);
    hist_kernel<<<(N_EDGES + 255) / 256, 256, 0, stream>>>(dst, deg);
    scan_phase1<<<SCAN_NBLK, 1024, 0, stream>>>(deg, blocksum);
    scan_phase2<<<1, 128, 0, stream>>>(blocksum, blockoff, offsets);
    scan_phase3<<<SCAN_NBLK, 1024, 0, stream>>>(deg, blockoff, offsets, cursor);
    fill_kernel<<<(N_EDGES + 255) / 256, 256, 0, stream>>>(src, dst, cursor, csr_src);
    gstart_kernel<<<(N_GRAPHS + 1 + 255) / 256, 256, 0, stream>>>(batch, gstart);
    cvt_x_kernel<<<(N_NODES * D) / (256 * 8), 256, 0, stream>>>(x, buf0);
    prep_w_kernel<<<dim3(128, 6), 128, 0, stream>>>(conv_W1, conv_W2, Wt);
    prep_fold_kernel<<<6, 128, 0, stream>>>(conv_b1, bn_gamma, bn_beta,
                                            bn_mean, bn_var, conv_b2, folds);

    const int GEMM_GRID = (N_NODES + 63) / 64;   // 1563
    ushort* cur = buf0;
    for (int l = 0; l < 3; ++l) {
        gather_bf16<<<N_NODES / 4, 256, 0, stream>>>(cur, offsets, csr_src, buf1);
        gemm_mfma<<<GEMM_GRID, 256, 0, stream>>>(buf1, buf2,
            Wt + (size_t)(2 * l) * D * D, folds + (size_t)(2 * l) * 2 * D);
        gemm_mfma<<<GEMM_GRID, 256, 0, stream>>>(buf2, cur == buf0 ? buf0 : buf0,
            Wt + (size_t)(2 * l + 1) * D * D, folds + (size_t)(2 * l + 1) * 2 * D);
        cur = buf0;
    }

    pool_kernel<<<N_GRAPHS, 128, 0, stream>>>(buf0, gstart, gpool);
    head_kernel<<<N_GRAPHS, 128, 0, stream>>>(gpool, head_W1, head_b1,
                                              head_W2, head_b2, out);
}

// Round 5
// 602.008 us; speedup vs baseline: 21.8055x; 1.1058x over previous
//
#include <hip/hip_runtime.h>

#define N_NODES  100000
#define N_EDGES  1600000
#define N_GRAPHS 1024
#define D        128
#define BN_EPS   1e-5f

#define SCAN_BLOCK 1024
#define SCAN_NBLK  ((N_NODES + SCAN_BLOCK - 1) / SCAN_BLOCK)   // 98

#define NSLICE      8
#define SLICE_NODES (N_NODES / NSLICE)   // 12500
#define SLICE_GRID  1024                  // 128 blocks per slice group

typedef short bf16x8 __attribute__((ext_vector_type(8)));
typedef float f32x4  __attribute__((ext_vector_type(4)));

__device__ __forceinline__ ushort f2bf(float f) {        // RNE fp32->bf16
    unsigned int b = __float_as_uint(f);
    return (ushort)((b + 0x7fffu + ((b >> 16) & 1u)) >> 16);
}
__device__ __forceinline__ float bflo(unsigned int u) { return __uint_as_float(u << 16); }
__device__ __forceinline__ float bfhi(unsigned int u) { return __uint_as_float(u & 0xffff0000u); }
__device__ __forceinline__ unsigned int packbf(float x, float y) {
    return (unsigned int)f2bf(x) | ((unsigned int)f2bf(y) << 16);
}

// ---------------- CSR build ----------------

__global__ void zero_kernel(int* __restrict__ p, int n) {
    int i = blockIdx.x * blockDim.x + threadIdx.x;
    if (i < n) p[i] = 0;
}

// XCD-sliced histogram: block b serves node slice (b&7); atomics stay in one
// XCD's L2 (50 KB region). Each slice group grid-strides the full edge list.
__global__ __launch_bounds__(256) void hist_sliced(const int* __restrict__ dst,
                                                   int* __restrict__ deg) {
    int slice = blockIdx.x & (NSLICE - 1);
    int lo = slice * SLICE_NODES, hi = lo + SLICE_NODES;
    int stride = (SLICE_GRID / NSLICE) * 256;
    int e0 = (blockIdx.x >> 3) * 256 + threadIdx.x;
    for (int e = e0; e < N_EDGES; e += stride) {
        int d = dst[e];
        if (d >= lo && d < hi) atomicAdd(&deg[d], 1);
    }
}

__global__ __launch_bounds__(1024) void scan_phase1(const int* __restrict__ deg,
                                                    int* __restrict__ blocksum) {
    __shared__ int red[16];
    int t = threadIdx.x;
    int i = blockIdx.x * SCAN_BLOCK + t;
    int v = (i < N_NODES) ? deg[i] : 0;
#pragma unroll
    for (int off = 32; off > 0; off >>= 1) v += __shfl_down(v, off, 64);
    if ((t & 63) == 0) red[t >> 6] = v;
    __syncthreads();
    if (t == 0) {
        int s = 0;
#pragma unroll
        for (int w = 0; w < 16; ++w) s += red[w];
        blocksum[blockIdx.x] = s;
    }
}

__global__ __launch_bounds__(128) void scan_phase2(const int* __restrict__ blocksum,
                                                   int* __restrict__ blockoff,
                                                   int* __restrict__ offsets) {
    __shared__ int part[128];
    int t = threadIdx.x;
    int v = (t < SCAN_NBLK) ? blocksum[t] : 0;
    part[t] = v;
    __syncthreads();
    for (int off = 1; off < 128; off <<= 1) {
        int u = (t >= off) ? part[t - off] : 0;
        __syncthreads();
        part[t] += u;
        __syncthreads();
    }
    if (t < SCAN_NBLK) blockoff[t] = part[t] - v;
    if (t == 0) offsets[N_NODES] = N_EDGES;
}

__global__ __launch_bounds__(1024) void scan_phase3(const int* __restrict__ deg,
                                                    const int* __restrict__ blockoff,
                                                    int* __restrict__ offsets,
                                                    int* __restrict__ cursor) {
    __shared__ int part[1024];
    int t = threadIdx.x;
    int i = blockIdx.x * SCAN_BLOCK + t;
    int v = (i < N_NODES) ? deg[i] : 0;
    part[t] = v;
    __syncthreads();
    for (int off = 1; off < 1024; off <<= 1) {
        int u = (t >= off) ? part[t - off] : 0;
        __syncthreads();
        part[t] += u;
        __syncthreads();
    }
    if (i < N_NODES) {
        int excl = blockoff[blockIdx.x] + part[t] - v;
        offsets[i] = excl;
        cursor[i]  = excl;
    }
}

// XCD-sliced bucket fill: csr_src writes land in one contiguous ~800 KB
// region per slice -> L2-resident, single eviction pass (kills the 16x
// write amplification seen in R4: WRITE_SIZE 105 MB for a 6.4 MB array).
__global__ __launch_bounds__(256) void fill_sliced(const int* __restrict__ src,
                                                   const int* __restrict__ dst,
                                                   int* __restrict__ cursor,
                                                   int* __restrict__ csr_src) {
    int slice = blockIdx.x & (NSLICE - 1);
    int lo = slice * SLICE_NODES, hi = lo + SLICE_NODES;
    int stride = (SLICE_GRID / NSLICE) * 256;
    int e0 = (blockIdx.x >> 3) * 256 + threadIdx.x;
    for (int e = e0; e < N_EDGES; e += stride) {
        int d = dst[e];
        if (d >= lo && d < hi) {
            int slot = atomicAdd(&cursor[d], 1);
            csr_src[slot] = src[e];
        }
    }
}

__global__ void gstart_kernel(const int* __restrict__ batch, int* __restrict__ gstart) {
    int g = blockIdx.x * blockDim.x + threadIdx.x;
    if (g > N_GRAPHS) return;
    int lo = 0, hi = N_NODES;
    while (lo < hi) {
        int mid = (lo + hi) >> 1;
        if (batch[mid] < g) lo = mid + 1; else hi = mid;
    }
    gstart[g] = lo;
}

// ---------------- precompute: x -> bf16, W -> bf16 transposed, BN folds ----------------

__global__ __launch_bounds__(256) void cvt_x_kernel(const float* __restrict__ x,
                                                    ushort* __restrict__ xb) {
    size_t i = ((size_t)blockIdx.x * 256 + threadIdx.x) * 8;   // 6250 blocks exact
    float4 v0 = *(const float4*)(x + i);
    float4 v1 = *(const float4*)(x + i + 4);
    uint4 o;
    o.x = packbf(v0.x, v0.y); o.y = packbf(v0.z, v0.w);
    o.z = packbf(v1.x, v1.y); o.w = packbf(v1.z, v1.w);
    *(uint4*)(xb + i) = o;
}

__global__ __launch_bounds__(128) void prep_w_kernel(const float* __restrict__ W1,
                                                     const float* __restrict__ W2,
                                                     ushort* __restrict__ Wt) {
    int i = blockIdx.y, k = blockIdx.x, n = threadIdx.x, l = i >> 1;
    const float* W = (i & 1) ? (W2 + (size_t)l * D * D) : (W1 + (size_t)l * D * D);
    Wt[(size_t)i * D * D + n * D + k] = f2bf(W[k * D + n]);
}

__global__ __launch_bounds__(128) void prep_fold_kernel(
        const float* __restrict__ b1, const float* __restrict__ gamma,
        const float* __restrict__ beta, const float* __restrict__ mean,
        const float* __restrict__ var, const float* __restrict__ b2,
        float* __restrict__ folds) {
    int i = blockIdx.x, j = threadIdx.x, l = i >> 1;
    float s, o;
    if ((i & 1) == 0) {
        float sv = gamma[l * D + j] * rsqrtf(var[l * D + j] + BN_EPS);
        s = sv;
        o = (b1[l * D + j] - mean[l * D + j]) * sv + beta[l * D + j];
    } else {
        s = 1.0f;
        o = b2[l * D + j];
    }
    folds[(size_t)i * 2 * D + j]     = s;
    folds[(size_t)i * 2 * D + D + j] = o;
}

// ---------------- aggregation (bf16 rows, fp32 accumulate, 8 outstanding loads) ----------------
__global__ __launch_bounds__(256) void gather_bf16(const ushort* __restrict__ xb,
                                                   const int* __restrict__ offsets,
                                                   const int* __restrict__ csr_src,
                                                   ushort* __restrict__ hb) {
    int wv = threadIdx.x >> 6, lane = threadIdx.x & 63;
    int node = blockIdx.x * 4 + wv;           // 25000*4 == N_NODES
    const unsigned int* base = (const unsigned int*)xb;
    unsigned int u = base[(size_t)node * 64 + lane];
    float ax = bflo(u), ay = bfhi(u);
    int b = offsets[node], e = offsets[node + 1];
    int i = b;
    for (; i + 7 < e; i += 8) {               // 8 outstanding row loads
        int s0 = csr_src[i],     s1 = csr_src[i + 1], s2 = csr_src[i + 2], s3 = csr_src[i + 3];
        int s4 = csr_src[i + 4], s5 = csr_src[i + 5], s6 = csr_src[i + 6], s7 = csr_src[i + 7];
        unsigned int v0 = base[(size_t)s0 * 64 + lane];
        unsigned int v1 = base[(size_t)s1 * 64 + lane];
        unsigned int v2 = base[(size_t)s2 * 64 + lane];
        unsigned int v3 = base[(size_t)s3 * 64 + lane];
        unsigned int v4 = base[(size_t)s4 * 64 + lane];
        unsigned int v5 = base[(size_t)s5 * 64 + lane];
        unsigned int v6 = base[(size_t)s6 * 64 + lane];
        unsigned int v7 = base[(size_t)s7 * 64 + lane];
        ax += bflo(v0) + bflo(v1) + bflo(v2) + bflo(v3)
            + bflo(v4) + bflo(v5) + bflo(v6) + bflo(v7);
        ay += bfhi(v0) + bfhi(v1) + bfhi(v2) + bfhi(v3)
            + bfhi(v4) + bfhi(v5) + bfhi(v6) + bfhi(v7);
    }
    for (; i + 3 < e; i += 4) {
        int s0 = csr_src[i], s1 = csr_src[i + 1], s2 = csr_src[i + 2], s3 = csr_src[i + 3];
        unsigned int v0 = base[(size_t)s0 * 64 + lane];
        unsigned int v1 = base[(size_t)s1 * 64 + lane];
        unsigned int v2 = base[(size_t)s2 * 64 + lane];
        unsigned int v3 = base[(size_t)s3 * 64 + lane];
        ax += bflo(v0) + bflo(v1) + bflo(v2) + bflo(v3);
        ay += bfhi(v0) + bfhi(v1) + bfhi(v2) + bfhi(v3);
    }
    for (; i < e; ++i) {
        unsigned int v = base[(size_t)csr_src[i] * 64 + lane];
        ax += bflo(v); ay += bfhi(v);
    }
    ((unsigned int*)hb)[(size_t)node * 64 + lane] = packbf(ax, ay);
}

// ---------------- MFMA GEMM: out = relu(in @ W * s + o), bf16 in/out ----------------
__global__ __launch_bounds__(256) void gemm_mfma(const ushort* __restrict__ in,
                                                 ushort* __restrict__ out,
                                                 const ushort* __restrict__ Wt,
                                                 const float* __restrict__ fold) {
    __shared__ ushort As[64 * 136];
    __shared__ ushort Bs[128 * 136];
    __shared__ ushort Cs[64 * 140];
    int t = threadIdx.x;
    int row0 = blockIdx.x * 64;               // 1563 blocks, last partial (32 rows)

#pragma unroll
    for (int i = 0; i < 4; ++i) {
        int f = t + 256 * i; int m = f >> 4, g = f & 15;
        *(float4*)(As + m * 136 + g * 8) = *(const float4*)(in + (size_t)(row0 + m) * D + g * 8);
    }
#pragma unroll
    for (int i = 0; i < 8; ++i) {
        int f = t + 256 * i; int n = f >> 4, g = f & 15;
        *(float4*)(Bs + n * 136 + g * 8) = *(const float4*)(Wt + (size_t)n * D + g * 8);
    }
    __syncthreads();

    int lane = t & 63, wv = t >> 6;
    int quad = lane >> 4, mr = lane & 15;
    int mbase = wv * 16;
    const ushort* ap = As + (mbase + mr) * 136 + quad * 8;
    bf16x8 a0 = *(const bf16x8*)(ap);
    bf16x8 a1 = *(const bf16x8*)(ap + 32);
    bf16x8 a2 = *(const bf16x8*)(ap + 64);
    bf16x8 a3 = *(const bf16x8*)(ap + 96);

#pragma unroll
    for (int nt = 0; nt < 8; ++nt) {
        const ushort* bq = Bs + (nt * 16 + mr) * 136 + quad * 8;
        bf16x8 b0 = *(const bf16x8*)(bq);
        bf16x8 b1 = *(const bf16x8*)(bq + 32);
        bf16x8 b2 = *(const bf16x8*)(bq + 64);
        bf16x8 b3 = *(const bf16x8*)(bq + 96);
        f32x4 acc = {0.f, 0.f, 0.f, 0.f};
        acc = __builtin_amdgcn_mfma_f32_16x16x32_bf16(a0, b0, acc, 0, 0, 0);
        acc = __builtin_amdgcn_mfma_f32_16x16x32_bf16(a1, b1, acc, 0, 0, 0);
        acc = __builtin_amdgcn_mfma_f32_16x16x32_bf16(a2, b2, acc, 0, 0, 0);
        acc = __builtin_amdgcn_mfma_f32_16x16x32_bf16(a3, b3, acc, 0, 0, 0);
        int j = nt * 16 + mr;                 // C/D: col=lane&15, row=quad*4+reg (m89)
        float s = fold[j], o = fold[D + j];
#pragma unroll
        for (int r = 0; r < 4; ++r) {
            float z = fmaf(acc[r], s, o);
            z = fmaxf(z, 0.0f);
            Cs[(mbase + quad * 4 + r) * 140 + j] = f2bf(z);
        }
    }
    __syncthreads();

#pragma unroll
    for (int i = 0; i < 8; ++i) {
        int f = t + 256 * i; int lr = f >> 5, g = f & 31;
        if (row0 + lr < N_NODES)
            *(float2*)(out + (size_t)(row0 + lr) * D + g * 4) =
                *(const float2*)(Cs + lr * 140 + g * 4);
    }
}

// ---------------- pooling (bf16 in, fp32 out) ----------------
__global__ __launch_bounds__(128) void pool_kernel(const ushort* __restrict__ xb,
                                                   const int* __restrict__ gstart,
                                                   float* __restrict__ g) {
    int gr = blockIdx.x, j = threadIdx.x;
    float acc = 0.0f;
    int b = gstart[gr], e = gstart[gr + 1];
    for (int i = b; i < e; ++i)
        acc += __uint_as_float(((unsigned int)xb[(size_t)i * D + j]) << 16);
    g[gr * D + j] = acc;
}

// ---------------- head (fp32) ----------------
__global__ __launch_bounds__(128) void head_kernel(const float* __restrict__ g,
                                                   const float* __restrict__ W1,
                                                   const float* __restrict__ b1,
                                                   const float* __restrict__ W2,
                                                   const float* __restrict__ b2,
                                                   float* __restrict__ out) {
    __shared__ float row[128];
    __shared__ float t1[128];
    int r = blockIdx.x, j = threadIdx.x;
    row[j] = g[r * D + j];
    __syncthreads();
    float acc = b1[j];
    for (int k = 0; k < D; ++k) acc = fmaf(row[k], W1[k * D + j], acc);
    t1[j] = fmaxf(acc, 0.0f);
    __syncthreads();
    float acc2 = b2[j];
    for (int k = 0; k < D; ++k) acc2 = fmaf(t1[k], W2[k * D + j], acc2);
    out[r * D + j] = acc2;
}

// ---------------- launcher ----------------
extern "C" void kernel_launch(void* const* d_in, const int* in_sizes, int n_in,
                              void* d_out, int out_size, void* d_ws, size_t ws_size,
                              hipStream_t stream) {
    const float* x        = (const float*)d_in[0];
    const int*   ei       = (const int*)d_in[1];
    const int*   src      = ei;
    const int*   dst      = ei + N_EDGES;
    const int*   batch    = (const int*)d_in[2];
    const float* conv_W1  = (const float*)d_in[3];
    const float* conv_b1  = (const float*)d_in[4];
    const float* bn_gamma = (const float*)d_in[5];
    const float* bn_beta  = (const float*)d_in[6];
    const float* bn_mean  = (const float*)d_in[7];
    const float* bn_var   = (const float*)d_in[8];
    const float* conv_W2  = (const float*)d_in[9];
    const float* conv_b2  = (const float*)d_in[10];
    const float* head_W1  = (const float*)d_in[11];
    const float* head_b1  = (const float*)d_in[12];
    const float* head_W2  = (const float*)d_in[13];
    const float* head_b2  = (const float*)d_in[14];
    float* out = (float*)d_out;

    char* ws = (char*)d_ws;
    size_t off = 0;
    auto alloc = [&](size_t bytes) -> void* {
        void* p = ws + off;
        off = (off + bytes + 255) & ~(size_t)255;
        return p;
    };
    const size_t NODE_BUF = (size_t)(N_NODES + 64) * D * sizeof(ushort);
    ushort* buf0    = (ushort*)alloc(NODE_BUF);
    ushort* buf1    = (ushort*)alloc(NODE_BUF);
    ushort* buf2    = (ushort*)alloc(NODE_BUF);
    ushort* Wt      = (ushort*)alloc((size_t)6 * D * D * sizeof(ushort));
    float*  folds   = (float*)alloc((size_t)6 * 2 * D * sizeof(float));
    int*   csr_src  = (int*)alloc((size_t)N_EDGES * sizeof(int));
    int*   offsets  = (int*)alloc((size_t)(N_NODES + 1) * sizeof(int));
    int*   cursor   = (int*)alloc((size_t)N_NODES * sizeof(int));
    int*   deg      = (int*)alloc((size_t)N_NODES * sizeof(int));
    int*   blocksum = (int*)alloc((size_t)SCAN_NBLK * sizeof(int));
    int*   blockoff = (int*)alloc((size_t)SCAN_NBLK * sizeof(int));
    int*   gstart   = (int*)alloc((size_t)(N_GRAPHS + 1) * sizeof(int));
    float* gpool    = (float*)alloc((size_t)N_GRAPHS * D * sizeof(float));

    zero_kernel<<<(N_NODES + 255) / 256, 256, 0, stream>>>(deg, N_NODES);
    hist_sliced<<<SLICE_GRID, 256, 0, stream>>>(dst, deg);
    scan_phase1<<<SCAN_NBLK, 1024, 0, stream>>>(deg, blocksum);
    scan_phase2<<<1, 128, 0, stream>>>(blocksum, blockoff, offsets);
    scan_phase3<<<SCAN_NBLK, 1024, 0, stream>>>(deg, blockoff, offsets, cursor);
    fill_sliced<<<SLICE_GRID, 256, 0, stream>>>(src, dst, cursor, csr_src);
    gstart_kernel<<<(N_GRAPHS + 1 + 255) / 256, 256, 0, stream>>>(batch, gstart);
    cvt_x_kernel<<<(N_NODES * D) / (256 * 8), 256, 0, stream>>>(x, buf0);
    prep_w_kernel<<<dim3(128, 6), 128, 0, stream>>>(conv_W1, conv_W2, Wt);
    prep_fold_kernel<<<6, 128, 0, stream>>>(conv_b1, bn_gamma, bn_beta,
                                            bn_mean, bn_var, conv_b2, folds);

    const int GEMM_GRID = (N_NODES + 63) / 64;   // 1563
    for (int l = 0; l < 3; ++l) {
        gather_bf16<<<N_NODES / 4, 256, 0, stream>>>(buf0, offsets, csr_src, buf1);
        gemm_mfma<<<GEMM_GRID, 256, 0, stream>>>(buf1, buf2,
            Wt + (size_t)(2 * l) * D * D, folds + (size_t)(2 * l) * 2 * D);
        gemm_mfma<<<GEMM_GRID, 256, 0, stream>>>(buf2, buf0,
            Wt + (size_t)(2 * l + 1) * D * D, folds + (size_t)(2 * l + 1) * 2 * D);
    }

    pool_kernel<<<N_GRAPHS, 128, 0, stream>>>(buf0, gstart, gpool);
    head_kernel<<<N_GRAPHS, 128, 0, stream>>>(gpool, head_W1, head_b1,
                                              head_W2, head_b2, out);
}

// Round 6
// 588.382 us; speedup vs baseline: 22.3105x; 1.0232x over previous
//
#include <hip/hip_runtime.h>

#define N_NODES  100000
#define N_EDGES  1600000
#define N_GRAPHS 1024
#define D        128
#define BN_EPS   1e-5f

#define SCAN_BLOCK 1024
#define SCAN_NBLK  ((N_NODES + SCAN_BLOCK - 1) / SCAN_BLOCK)   // 98

#define NSLICE      8
#define SLICE_NODES (N_NODES / NSLICE)   // 12500
#define SLICE_CAP   204800               // mean 200000, ~11 sigma slack
#define QCAP        384                  // per-slice LDS queue (mean 250, ~9 sigma)
#define CCHUNK      2000
#define CGRID       800                  // 800*2000 == N_EDGES
#define SLICE_GRID  1024

typedef short bf16x8 __attribute__((ext_vector_type(8)));
typedef float f32x4  __attribute__((ext_vector_type(4)));

__device__ __forceinline__ ushort f2bf(float f) {        // RNE fp32->bf16
    unsigned int b = __float_as_uint(f);
    return (ushort)((b + 0x7fffu + ((b >> 16) & 1u)) >> 16);
}
__device__ __forceinline__ float bflo(unsigned int u) { return __uint_as_float(u << 16); }
__device__ __forceinline__ float bfhi(unsigned int u) { return __uint_as_float(u & 0xffff0000u); }
__device__ __forceinline__ unsigned int packbf(float x, float y) {
    return (unsigned int)f2bf(x) | ((unsigned int)f2bf(y) << 16);
}

// ---------------- CSR build ----------------

__global__ void zero_kernel(int* __restrict__ p, int n) {
    int i = blockIdx.x * blockDim.x + threadIdx.x;
    if (i < n) p[i] = 0;
}

// Pass 1: read edges ONCE, bin by slice in LDS, bulk-append packed
// (dst_local<<17 | src) to per-slice global queues (coalesced writes).
__global__ __launch_bounds__(256) void compact_kernel(const int* __restrict__ src,
                                                      const int* __restrict__ dst,
                                                      unsigned int* __restrict__ squeue,
                                                      int* __restrict__ slice_tail) {
    __shared__ unsigned int qbuf[NSLICE * QCAP];
    __shared__ int qcnt[NSLICE];
    __shared__ int qbase[NSLICE];
    int t = threadIdx.x;
    if (t < NSLICE) qcnt[t] = 0;
    __syncthreads();
    int e0 = blockIdx.x * CCHUNK;
    int eend = e0 + CCHUNK; if (eend > N_EDGES) eend = N_EDGES;
    for (int e = e0 + t; e < eend; e += 256) {
        int d = dst[e], s = src[e];
        int sl = d / SLICE_NODES;
        unsigned int pk = ((unsigned int)(d - sl * SLICE_NODES) << 17) | (unsigned int)s;
        int pos = atomicAdd(&qcnt[sl], 1);
        if (pos < QCAP) qbuf[sl * QCAP + pos] = pk;
        else {  // ~never: direct spill
            int gp = atomicAdd(&slice_tail[sl], 1);
            squeue[(size_t)sl * SLICE_CAP + gp] = pk;
        }
    }
    __syncthreads();
    if (t < NSLICE) {
        int n = qcnt[t]; if (n > QCAP) n = QCAP;
        qbase[t] = atomicAdd(&slice_tail[t], n);
    }
    __syncthreads();
    for (int sl = 0; sl < NSLICE; ++sl) {
        int n = qcnt[sl]; if (n > QCAP) n = QCAP;
        int gb = qbase[sl];
        for (int i = t; i < n; i += 256)
            squeue[(size_t)sl * SLICE_CAP + gb + i] = qbuf[sl * QCAP + i];
    }
}

// Pass 2: sliced histogram from the compact queues (L2-local reads+atomics).
__global__ __launch_bounds__(256) void hist_q(const unsigned int* __restrict__ squeue,
                                              const int* __restrict__ slice_tail,
                                              int* __restrict__ deg) {
    int slice = blockIdx.x & (NSLICE - 1);
    int n = slice_tail[slice];
    size_t base = (size_t)slice * SLICE_CAP;
    int stride = (SLICE_GRID / NSLICE) * 256;
    for (int i = (blockIdx.x >> 3) * 256 + threadIdx.x; i < n; i += stride) {
        unsigned int p = squeue[base + i];
        atomicAdd(&deg[(int)(p >> 17) + slice * SLICE_NODES], 1);
    }
}

__global__ __launch_bounds__(1024) void scan_phase1(const int* __restrict__ deg,
                                                    int* __restrict__ blocksum) {
    __shared__ int red[16];
    int t = threadIdx.x;
    int i = blockIdx.x * SCAN_BLOCK + t;
    int v = (i < N_NODES) ? deg[i] : 0;
#pragma unroll
    for (int off = 32; off > 0; off >>= 1) v += __shfl_down(v, off, 64);
    if ((t & 63) == 0) red[t >> 6] = v;
    __syncthreads();
    if (t == 0) {
        int s = 0;
#pragma unroll
        for (int w = 0; w < 16; ++w) s += red[w];
        blocksum[blockIdx.x] = s;
    }
}

__global__ __launch_bounds__(128) void scan_phase2(const int* __restrict__ blocksum,
                                                   int* __restrict__ blockoff,
                                                   int* __restrict__ offsets) {
    __shared__ int part[128];
    int t = threadIdx.x;
    int v = (t < SCAN_NBLK) ? blocksum[t] : 0;
    part[t] = v;
    __syncthreads();
    for (int off = 1; off < 128; off <<= 1) {
        int u = (t >= off) ? part[t - off] : 0;
        __syncthreads();
        part[t] += u;
        __syncthreads();
    }
    if (t < SCAN_NBLK) blockoff[t] = part[t] - v;
    if (t == 0) offsets[N_NODES] = N_EDGES;
}

__global__ __launch_bounds__(1024) void scan_phase3(const int* __restrict__ deg,
                                                    const int* __restrict__ blockoff,
                                                    int* __restrict__ offsets,
                                                    int* __restrict__ cursor) {
    __shared__ int part[1024];
    int t = threadIdx.x;
    int i = blockIdx.x * SCAN_BLOCK + t;
    int v = (i < N_NODES) ? deg[i] : 0;
    part[t] = v;
    __syncthreads();
    for (int off = 1; off < 1024; off <<= 1) {
        int u = (t >= off) ? part[t - off] : 0;
        __syncthreads();
        part[t] += u;
        __syncthreads();
    }
    if (i < N_NODES) {
        int excl = blockoff[blockIdx.x] + part[t] - v;
        offsets[i] = excl;
        cursor[i]  = excl;
    }
}

// Pass 3: sliced bucket fill from compact queues. Only ~800 KB of reads per
// slice stream through L2 -> csr_src write lines stay resident until full.
__global__ __launch_bounds__(256) void fill_q(const unsigned int* __restrict__ squeue,
                                              const int* __restrict__ slice_tail,
                                              int* __restrict__ cursor,
                                              int* __restrict__ csr_src) {
    int slice = blockIdx.x & (NSLICE - 1);
    int n = slice_tail[slice];
    size_t base = (size_t)slice * SLICE_CAP;
    int stride = (SLICE_GRID / NSLICE) * 256;
    for (int i = (blockIdx.x >> 3) * 256 + threadIdx.x; i < n; i += stride) {
        unsigned int p = squeue[base + i];
        int d = (int)(p >> 17) + slice * SLICE_NODES;
        int slot = atomicAdd(&cursor[d], 1);
        csr_src[slot] = (int)(p & 0x1FFFFu);
    }
}

__global__ void gstart_kernel(const int* __restrict__ batch, int* __restrict__ gstart) {
    int g = blockIdx.x * blockDim.x + threadIdx.x;
    if (g > N_GRAPHS) return;
    int lo = 0, hi = N_NODES;
    while (lo < hi) {
        int mid = (lo + hi) >> 1;
        if (batch[mid] < g) lo = mid + 1; else hi = mid;
    }
    gstart[g] = lo;
}

// ---------------- precompute ----------------

__global__ __launch_bounds__(256) void cvt_x_kernel(const float* __restrict__ x,
                                                    ushort* __restrict__ xb) {
    size_t i = ((size_t)blockIdx.x * 256 + threadIdx.x) * 8;   // 6250 blocks exact
    float4 v0 = *(const float4*)(x + i);
    float4 v1 = *(const float4*)(x + i + 4);
    uint4 o;
    o.x = packbf(v0.x, v0.y); o.y = packbf(v0.z, v0.w);
    o.z = packbf(v1.x, v1.y); o.w = packbf(v1.z, v1.w);
    *(uint4*)(xb + i) = o;
}

__global__ __launch_bounds__(128) void prep_w_kernel(const float* __restrict__ W1,
                                                     const float* __restrict__ W2,
                                                     ushort* __restrict__ Wt) {
    int i = blockIdx.y, k = blockIdx.x, n = threadIdx.x, l = i >> 1;
    const float* W = (i & 1) ? (W2 + (size_t)l * D * D) : (W1 + (size_t)l * D * D);
    Wt[(size_t)i * D * D + n * D + k] = f2bf(W[k * D + n]);
}

__global__ __launch_bounds__(128) void prep_fold_kernel(
        const float* __restrict__ b1, const float* __restrict__ gamma,
        const float* __restrict__ beta, const float* __restrict__ mean,
        const float* __restrict__ var, const float* __restrict__ b2,
        float* __restrict__ folds) {
    int i = blockIdx.x, j = threadIdx.x, l = i >> 1;
    float s, o;
    if ((i & 1) == 0) {
        float sv = gamma[l * D + j] * rsqrtf(var[l * D + j] + BN_EPS);
        s = sv;
        o = (b1[l * D + j] - mean[l * D + j]) * sv + beta[l * D + j];
    } else {
        s = 1.0f;
        o = b2[l * D + j];
    }
    folds[(size_t)i * 2 * D + j]     = s;
    folds[(size_t)i * 2 * D + D + j] = o;
}

// ---------------- aggregation (bf16 rows, fp32 accumulate, 8 outstanding) ----------------
__global__ __launch_bounds__(256) void gather_bf16(const ushort* __restrict__ xb,
                                                   const int* __restrict__ offsets,
                                                   const int* __restrict__ csr_src,
                                                   ushort* __restrict__ hb) {
    int wv = threadIdx.x >> 6, lane = threadIdx.x & 63;
    int node = blockIdx.x * 4 + wv;           // 25000*4 == N_NODES
    const unsigned int* base = (const unsigned int*)xb;
    unsigned int u = base[(size_t)node * 64 + lane];
    float ax = bflo(u), ay = bfhi(u);
    int b = offsets[node], e = offsets[node + 1];
    int i = b;
    for (; i + 7 < e; i += 8) {
        int s0 = csr_src[i],     s1 = csr_src[i + 1], s2 = csr_src[i + 2], s3 = csr_src[i + 3];
        int s4 = csr_src[i + 4], s5 = csr_src[i + 5], s6 = csr_src[i + 6], s7 = csr_src[i + 7];
        unsigned int v0 = base[(size_t)s0 * 64 + lane];
        unsigned int v1 = base[(size_t)s1 * 64 + lane];
        unsigned int v2 = base[(size_t)s2 * 64 + lane];
        unsigned int v3 = base[(size_t)s3 * 64 + lane];
        unsigned int v4 = base[(size_t)s4 * 64 + lane];
        unsigned int v5 = base[(size_t)s5 * 64 + lane];
        unsigned int v6 = base[(size_t)s6 * 64 + lane];
        unsigned int v7 = base[(size_t)s7 * 64 + lane];
        ax += bflo(v0) + bflo(v1) + bflo(v2) + bflo(v3)
            + bflo(v4) + bflo(v5) + bflo(v6) + bflo(v7);
        ay += bfhi(v0) + bfhi(v1) + bfhi(v2) + bfhi(v3)
            + bfhi(v4) + bfhi(v5) + bfhi(v6) + bfhi(v7);
    }
    for (; i + 3 < e; i += 4) {
        int s0 = csr_src[i], s1 = csr_src[i + 1], s2 = csr_src[i + 2], s3 = csr_src[i + 3];
        unsigned int v0 = base[(size_t)s0 * 64 + lane];
        unsigned int v1 = base[(size_t)s1 * 64 + lane];
        unsigned int v2 = base[(size_t)s2 * 64 + lane];
        unsigned int v3 = base[(size_t)s3 * 64 + lane];
        ax += bflo(v0) + bflo(v1) + bflo(v2) + bflo(v3);
        ay += bfhi(v0) + bfhi(v1) + bfhi(v2) + bfhi(v3);
    }
    for (; i < e; ++i) {
        unsigned int v = base[(size_t)csr_src[i] * 64 + lane];
        ax += bflo(v); ay += bfhi(v);
    }
    ((unsigned int*)hb)[(size_t)node * 64 + lane] = packbf(ax, ay);
}

// ---------------- fused layer: out = relu(relu(BN(in@W1))@W2 + b2) ----------------
// 512 thr (8 waves), 128x128 tile, wave = 16 rows. H stays in LDS (As region).
// Cs aliases Bs1 (freed after the gemm1 barrier).
__global__ __launch_bounds__(512) void fused_gemm(const ushort* __restrict__ in,
                                                  ushort* __restrict__ out,
                                                  const ushort* __restrict__ Wt1,
                                                  const ushort* __restrict__ Wt2,
                                                  const float* __restrict__ fold1,
                                                  const float* __restrict__ fold2) {
    __shared__ ushort As[128 * 136];    // A tile, then H tile
    __shared__ ushort Bs1[128 * 136];   // W1^T, then C staging
    __shared__ ushort Bs2[128 * 136];   // W2^T
    ushort* Cs = Bs1;
    int t = threadIdx.x;
    int row0 = blockIdx.x * 128;        // 782 blocks, last partial (32 rows)

#pragma unroll
    for (int i = 0; i < 4; ++i) {
        int f = t + 512 * i; int m = f >> 4, g = f & 15;
        *(float4*)(As + m * 136 + g * 8) = *(const float4*)(in + (size_t)(row0 + m) * D + g * 8);
        *(float4*)(Bs1 + m * 136 + g * 8) = *(const float4*)(Wt1 + (size_t)m * D + g * 8);
        *(float4*)(Bs2 + m * 136 + g * 8) = *(const float4*)(Wt2 + (size_t)m * D + g * 8);
    }
    __syncthreads();

    int lane = t & 63, wv = t >> 6;
    int quad = lane >> 4, mr = lane & 15;
    int mbase = wv * 16;
    const ushort* ap = As + (mbase + mr) * 136 + quad * 8;
    bf16x8 a0 = *(const bf16x8*)(ap);
    bf16x8 a1 = *(const bf16x8*)(ap + 32);
    bf16x8 a2 = *(const bf16x8*)(ap + 64);
    bf16x8 a3 = *(const bf16x8*)(ap + 96);
    __syncthreads();                    // all waves hold A-frags; As reusable for H

    // --- GEMM1: H = relu(BN(A@W1)), H -> As (each wave writes only own rows)
#pragma unroll
    for (int nt = 0; nt < 8; ++nt) {
        const ushort* bq = Bs1 + (nt * 16 + mr) * 136 + quad * 8;
        bf16x8 b0 = *(const bf16x8*)(bq);
        bf16x8 b1 = *(const bf16x8*)(bq + 32);
        bf16x8 b2 = *(const bf16x8*)(bq + 64);
        bf16x8 b3 = *(const bf16x8*)(bq + 96);
        f32x4 acc = {0.f, 0.f, 0.f, 0.f};
        acc = __builtin_amdgcn_mfma_f32_16x16x32_bf16(a0, b0, acc, 0, 0, 0);
        acc = __builtin_amdgcn_mfma_f32_16x16x32_bf16(a1, b1, acc, 0, 0, 0);
        acc = __builtin_amdgcn_mfma_f32_16x16x32_bf16(a2, b2, acc, 0, 0, 0);
        acc = __builtin_amdgcn_mfma_f32_16x16x32_bf16(a3, b3, acc, 0, 0, 0);
        int j = nt * 16 + mr;           // C/D: col=lane&15, row=quad*4+reg (m89)
        float s = fold1[j], o = fold1[D + j];
#pragma unroll
        for (int r = 0; r < 4; ++r) {
            float z = fmaxf(fmaf(acc[r], s, o), 0.0f);
            As[(mbase + quad * 4 + r) * 136 + j] = f2bf(z);
        }
    }
    __syncthreads();                    // gemm1 done everywhere -> Bs1 free (Cs)

    // --- GEMM2: out = relu(H@W2 + b2)
    const ushort* hp = As + (mbase + mr) * 136 + quad * 8;
    bf16x8 h0 = *(const bf16x8*)(hp);
    bf16x8 h1 = *(const bf16x8*)(hp + 32);
    bf16x8 h2 = *(const bf16x8*)(hp + 64);
    bf16x8 h3 = *(const bf16x8*)(hp + 96);
#pragma unroll
    for (int nt = 0; nt < 8; ++nt) {
        const ushort* bq = Bs2 + (nt * 16 + mr) * 136 + quad * 8;
        bf16x8 b0 = *(const bf16x8*)(bq);
        bf16x8 b1 = *(const bf16x8*)(bq + 32);
        bf16x8 b2 = *(const bf16x8*)(bq + 64);
        bf16x8 b3 = *(const bf16x8*)(bq + 96);
        f32x4 acc = {0.f, 0.f, 0.f, 0.f};
        acc = __builtin_amdgcn_mfma_f32_16x16x32_bf16(h0, b0, acc, 0, 0, 0);
        acc = __builtin_amdgcn_mfma_f32_16x16x32_bf16(h1, b1, acc, 0, 0, 0);
        acc = __builtin_amdgcn_mfma_f32_16x16x32_bf16(h2, b2, acc, 0, 0, 0);
        acc = __builtin_amdgcn_mfma_f32_16x16x32_bf16(h3, b3, acc, 0, 0, 0);
        int j = nt * 16 + mr;
        float o = fold2[D + j];
#pragma unroll
        for (int r = 0; r < 4; ++r) {
            float z = fmaxf(acc[r] + o, 0.0f);
            Cs[(mbase + quad * 4 + r) * 136 + j] = f2bf(z);
        }
    }
    __syncthreads();

#pragma unroll
    for (int i = 0; i < 8; ++i) {       // coalesced copy-out, float2 = 4 bf16
        int f = t + 512 * i; int lr = f >> 5, g = f & 31;
        if (row0 + lr < N_NODES)
            *(float2*)(out + (size_t)(row0 + lr) * D + g * 4) =
                *(const float2*)(Cs + lr * 136 + g * 4);
    }
}

// ---------------- pooling (bf16 in, fp32 out) ----------------
__global__ __launch_bounds__(128) void pool_kernel(const ushort* __restrict__ xb,
                                                   const int* __restrict__ gstart,
                                                   float* __restrict__ g) {
    int gr = blockIdx.x, j = threadIdx.x;
    float acc = 0.0f;
    int b = gstart[gr], e = gstart[gr + 1];
    for (int i = b; i < e; ++i)
        acc += __uint_as_float(((unsigned int)xb[(size_t)i * D + j]) << 16);
    g[gr * D + j] = acc;
}

// ---------------- head (fp32) ----------------
__global__ __launch_bounds__(128) void head_kernel(const float* __restrict__ g,
                                                   const float* __restrict__ W1,
                                                   const float* __restrict__ b1,
                                                   const float* __restrict__ W2,
                                                   const float* __restrict__ b2,
                                                   float* __restrict__ out) {
    __shared__ float row[128];
    __shared__ float t1[128];
    int r = blockIdx.x, j = threadIdx.x;
    row[j] = g[r * D + j];
    __syncthreads();
    float acc = b1[j];
    for (int k = 0; k < D; ++k) acc = fmaf(row[k], W1[k * D + j], acc);
    t1[j] = fmaxf(acc, 0.0f);
    __syncthreads();
    float acc2 = b2[j];
    for (int k = 0; k < D; ++k) acc2 = fmaf(t1[k], W2[k * D + j], acc2);
    out[r * D + j] = acc2;
}

// ---------------- launcher ----------------
extern "C" void kernel_launch(void* const* d_in, const int* in_sizes, int n_in,
                              void* d_out, int out_size, void* d_ws, size_t ws_size,
                              hipStream_t stream) {
    const float* x        = (const float*)d_in[0];
    const int*   ei       = (const int*)d_in[1];
    const int*   src      = ei;
    const int*   dst      = ei + N_EDGES;
    const int*   batch    = (const int*)d_in[2];
    const float* conv_W1  = (const float*)d_in[3];
    const float* conv_b1  = (const float*)d_in[4];
    const float* bn_gamma = (const float*)d_in[5];
    const float* bn_beta  = (const float*)d_in[6];
    const float* bn_mean  = (const float*)d_in[7];
    const float* bn_var   = (const float*)d_in[8];
    const float* conv_W2  = (const float*)d_in[9];
    const float* conv_b2  = (const float*)d_in[10];
    const float* head_W1  = (const float*)d_in[11];
    const float* head_b1  = (const float*)d_in[12];
    const float* head_W2  = (const float*)d_in[13];
    const float* head_b2  = (const float*)d_in[14];
    float* out = (float*)d_out;

    char* ws = (char*)d_ws;
    size_t off = 0;
    auto alloc = [&](size_t bytes) -> void* {
        void* p = ws + off;
        off = (off + bytes + 255) & ~(size_t)255;
        return p;
    };
    const size_t NODE_BUF = (size_t)(N_NODES + 128) * D * sizeof(ushort);
    ushort* buf0    = (ushort*)alloc(NODE_BUF);
    ushort* buf1    = (ushort*)alloc(NODE_BUF);
    ushort* Wt      = (ushort*)alloc((size_t)6 * D * D * sizeof(ushort));
    float*  folds   = (float*)alloc((size_t)6 * 2 * D * sizeof(float));
    unsigned int* squeue = (unsigned int*)alloc((size_t)NSLICE * SLICE_CAP * sizeof(unsigned int));
    int*   csr_src  = (int*)alloc((size_t)N_EDGES * sizeof(int));
    int*   offsets  = (int*)alloc((size_t)(N_NODES + 1) * sizeof(int));
    int*   cursor   = (int*)alloc((size_t)N_NODES * sizeof(int));
    int*   deg      = (int*)alloc((size_t)(N_NODES + NSLICE) * sizeof(int));
    int*   slice_tail = deg + N_NODES;   // zeroed together with deg
    int*   blocksum = (int*)alloc((size_t)SCAN_NBLK * sizeof(int));
    int*   blockoff = (int*)alloc((size_t)SCAN_NBLK * sizeof(int));
    int*   gstart   = (int*)alloc((size_t)(N_GRAPHS + 1) * sizeof(int));
    float* gpool    = (float*)alloc((size_t)N_GRAPHS * D * sizeof(float));

    zero_kernel<<<(N_NODES + NSLICE + 255) / 256, 256, 0, stream>>>(deg, N_NODES + NSLICE);
    compact_kernel<<<CGRID, 256, 0, stream>>>(src, dst, squeue, slice_tail);
    hist_q<<<SLICE_GRID, 256, 0, stream>>>(squeue, slice_tail, deg);
    scan_phase1<<<SCAN_NBLK, 1024, 0, stream>>>(deg, blocksum);
    scan_phase2<<<1, 128, 0, stream>>>(blocksum, blockoff, offsets);
    scan_phase3<<<SCAN_NBLK, 1024, 0, stream>>>(deg, blockoff, offsets, cursor);
    fill_q<<<SLICE_GRID, 256, 0, stream>>>(squeue, slice_tail, cursor, csr_src);
    gstart_kernel<<<(N_GRAPHS + 1 + 255) / 256, 256, 0, stream>>>(batch, gstart);
    cvt_x_kernel<<<(N_NODES * D) / (256 * 8), 256, 0, stream>>>(x, buf0);
    prep_w_kernel<<<dim3(128, 6), 128, 0, stream>>>(conv_W1, conv_W2, Wt);
    prep_fold_kernel<<<6, 128, 0, stream>>>(conv_b1, bn_gamma, bn_beta,
                                            bn_mean, bn_var, conv_b2, folds);

    const int FUSED_GRID = (N_NODES + 127) / 128;   // 782
    for (int l = 0; l < 3; ++l) {
        gather_bf16<<<N_NODES / 4, 256, 0, stream>>>(buf0, offsets, csr_src, buf1);
        fused_gemm<<<FUSED_GRID, 512, 0, stream>>>(buf1, buf0,
            Wt + (size_t)(2 * l) * D * D, Wt + (size_t)(2 * l + 1) * D * D,
            folds + (size_t)(2 * l) * 2 * D, folds + (size_t)(2 * l + 1) * 2 * D);
    }

    pool_kernel<<<N_GRAPHS, 128, 0, stream>>>(buf0, gstart, gpool);
    head_kernel<<<N_GRAPHS, 128, 0, stream>>>(gpool, head_W1, head_b1,
                                              head_W2, head_b2, out);
}

// Round 7
// 478.611 us; speedup vs baseline: 27.4275x; 1.2294x over previous
//
#include <hip/hip_runtime.h>

#define N_NODES  100000
#define N_EDGES  1600000
#define N_GRAPHS 1024
#define D        128
#define BN_EPS   1e-5f

// --- atomic-free CSR build geometry ---
#define FNSLICE      98                  // ceil(100000/1024) node slices
#define FSLICE_NODES 1024                // nodes per slice (d>>10)
#define FSLICE_CAP   20480               // queue cap: mean 16384, sigma~127 -> +32 sigma
#define QCAP         96                  // per-block LDS bin: mean 41, +12 sigma
#define CCHUNK       4000
#define CGRID        400                 // 400*4000 == N_EDGES

typedef short bf16x8 __attribute__((ext_vector_type(8)));
typedef float f32x4  __attribute__((ext_vector_type(4)));

__device__ __forceinline__ ushort f2bf(float f) {        // RNE fp32->bf16
    unsigned int b = __float_as_uint(f);
    return (ushort)((b + 0x7fffu + ((b >> 16) & 1u)) >> 16);
}
__device__ __forceinline__ float bflo(unsigned int u) { return __uint_as_float(u << 16); }
__device__ __forceinline__ float bfhi(unsigned int u) { return __uint_as_float(u & 0xffff0000u); }
__device__ __forceinline__ unsigned int packbf(float x, float y) {
    return (unsigned int)f2bf(x) | ((unsigned int)f2bf(y) << 16);
}

// ---------------- CSR build (no global atomics on hot paths) ----------------

__global__ void zero_kernel(int* __restrict__ p, int n) {
    int i = blockIdx.x * blockDim.x + threadIdx.x;
    if (i < n) p[i] = 0;
}

// Pass 1: read edges ONCE, bin by 1024-node slice in LDS, bulk-append packed
// (d_local<<17 | src) to per-slice global queues. Global atomics: only the
// ~39K slice_tail reservations (bulk, one per block x slice).
__global__ __launch_bounds__(256) void compact_kernel(const int* __restrict__ src,
                                                      const int* __restrict__ dst,
                                                      unsigned int* __restrict__ squeue,
                                                      int* __restrict__ slice_tail) {
    __shared__ unsigned int qbuf[FNSLICE * QCAP];   // 37.6 KB
    __shared__ int qcnt[FNSLICE];
    __shared__ int qbase[FNSLICE];
    int t = threadIdx.x;
    for (int i = t; i < FNSLICE; i += 256) qcnt[i] = 0;
    __syncthreads();
    int e0 = blockIdx.x * CCHUNK;
    int eend = e0 + CCHUNK; if (eend > N_EDGES) eend = N_EDGES;
    for (int e = e0 + t; e < eend; e += 256) {
        int d = dst[e], s = src[e];
        int sl = d >> 10;
        unsigned int pk = ((unsigned int)(d & 1023) << 17) | (unsigned int)s;
        int pos = atomicAdd(&qcnt[sl], 1);
        if (pos < QCAP) qbuf[sl * QCAP + pos] = pk;
        else {  // ~never (12-sigma): direct spill, still correct
            int gp = atomicAdd(&slice_tail[sl], 1);
            squeue[(size_t)sl * FSLICE_CAP + gp] = pk;
        }
    }
    __syncthreads();
    for (int i = t; i < FNSLICE; i += 256) {
        int n = qcnt[i]; if (n > QCAP) n = QCAP;
        qbase[i] = atomicAdd(&slice_tail[i], n);
    }
    __syncthreads();
    for (int sl = 0; sl < FNSLICE; ++sl) {
        int n = qcnt[sl]; if (n > QCAP) n = QCAP;
        int gb = qbase[sl];
        for (int i = t; i < n; i += 256)
            squeue[(size_t)sl * FSLICE_CAP + gb + i] = qbuf[sl * QCAP + i];
    }
}

// Pass 2: exclusive scan of the 98 slice totals (one tiny block).
__global__ __launch_bounds__(128) void slice_scan(const int* __restrict__ slice_tail,
                                                  int* __restrict__ slice_base,
                                                  int* __restrict__ offsets) {
    __shared__ int part[128];
    int t = threadIdx.x;
    int v = (t < FNSLICE) ? slice_tail[t] : 0;
    part[t] = v;
    __syncthreads();
    for (int off = 1; off < 128; off <<= 1) {
        int u = (t >= off) ? part[t - off] : 0;
        __syncthreads();
        part[t] += u;
        __syncthreads();
    }
    if (t < FNSLICE) slice_base[t] = part[t] - v;
    if (t == 0) offsets[N_NODES] = N_EDGES;
}

// Pass 3: one workgroup per slice does hist -> scan -> fill with LDS atomics
// ONLY. csr_src writes go to the block's private contiguous ~64 KB region;
// offsets written coalesced. Zero global atomics (the R6 WRITE_SIZE lesson:
// device-scope global atomics execute memory-side on multi-XCD -> ~40 B HBM
// traffic each; 1.6M of them was the 58 MB write excess).
__global__ __launch_bounds__(1024) void fill_local(const unsigned int* __restrict__ squeue,
                                                   const int* __restrict__ slice_tail,
                                                   const int* __restrict__ slice_base,
                                                   int* __restrict__ offsets,
                                                   int* __restrict__ csr_src) {
    __shared__ int hist[FSLICE_NODES];
    __shared__ int cur[FSLICE_NODES];
    int sl = blockIdx.x, t = threadIdx.x;
    int n = slice_tail[sl];
    size_t qb = (size_t)sl * FSLICE_CAP;
    int gbase = slice_base[sl];
    hist[t] = 0;
    __syncthreads();
    for (int i = t; i < n; i += 1024)
        atomicAdd(&hist[squeue[qb + i] >> 17], 1);
    __syncthreads();
    int v = hist[t];
    for (int off = 1; off < 1024; off <<= 1) {       // inclusive Hillis-Steele
        int u = (t >= off) ? hist[t - off] : 0;
        __syncthreads();
        hist[t] += u;
        __syncthreads();
    }
    int excl = hist[t] - v;
    cur[t] = excl;
    int node = sl * FSLICE_NODES + t;
    if (node < N_NODES) offsets[node] = gbase + excl;
    __syncthreads();
    for (int i = t; i < n; i += 1024) {
        unsigned int p = squeue[qb + i];
        int slot = atomicAdd(&cur[p >> 17], 1);      // LDS atomic
        csr_src[gbase + slot] = (int)(p & 0x1FFFFu);
    }
}

__global__ void gstart_kernel(const int* __restrict__ batch, int* __restrict__ gstart) {
    int g = blockIdx.x * blockDim.x + threadIdx.x;
    if (g > N_GRAPHS) return;
    int lo = 0, hi = N_NODES;
    while (lo < hi) {
        int mid = (lo + hi) >> 1;
        if (batch[mid] < g) lo = mid + 1; else hi = mid;
    }
    gstart[g] = lo;
}

// ---------------- precompute ----------------

__global__ __launch_bounds__(256) void cvt_x_kernel(const float* __restrict__ x,
                                                    ushort* __restrict__ xb) {
    size_t i = ((size_t)blockIdx.x * 256 + threadIdx.x) * 8;   // 6250 blocks exact
    float4 v0 = *(const float4*)(x + i);
    float4 v1 = *(const float4*)(x + i + 4);
    uint4 o;
    o.x = packbf(v0.x, v0.y); o.y = packbf(v0.z, v0.w);
    o.z = packbf(v1.x, v1.y); o.w = packbf(v1.z, v1.w);
    *(uint4*)(xb + i) = o;
}

__global__ __launch_bounds__(128) void prep_w_kernel(const float* __restrict__ W1,
                                                     const float* __restrict__ W2,
                                                     ushort* __restrict__ Wt) {
    int i = blockIdx.y, k = blockIdx.x, n = threadIdx.x, l = i >> 1;
    const float* W = (i & 1) ? (W2 + (size_t)l * D * D) : (W1 + (size_t)l * D * D);
    Wt[(size_t)i * D * D + n * D + k] = f2bf(W[k * D + n]);
}

__global__ __launch_bounds__(128) void prep_fold_kernel(
        const float* __restrict__ b1, const float* __restrict__ gamma,
        const float* __restrict__ beta, const float* __restrict__ mean,
        const float* __restrict__ var, const float* __restrict__ b2,
        float* __restrict__ folds) {
    int i = blockIdx.x, j = threadIdx.x, l = i >> 1;
    float s, o;
    if ((i & 1) == 0) {
        float sv = gamma[l * D + j] * rsqrtf(var[l * D + j] + BN_EPS);
        s = sv;
        o = (b1[l * D + j] - mean[l * D + j]) * sv + beta[l * D + j];
    } else {
        s = 1.0f;
        o = b2[l * D + j];
    }
    folds[(size_t)i * 2 * D + j]     = s;
    folds[(size_t)i * 2 * D + D + j] = o;
}

// ---------------- aggregation (bf16 rows, fp32 accumulate, 8 outstanding) ----------------
__global__ __launch_bounds__(256) void gather_bf16(const ushort* __restrict__ xb,
                                                   const int* __restrict__ offsets,
                                                   const int* __restrict__ csr_src,
                                                   ushort* __restrict__ hb) {
    int wv = threadIdx.x >> 6, lane = threadIdx.x & 63;
    int node = blockIdx.x * 4 + wv;           // 25000*4 == N_NODES
    const unsigned int* base = (const unsigned int*)xb;
    unsigned int u = base[(size_t)node * 64 + lane];
    float ax = bflo(u), ay = bfhi(u);
    int b = offsets[node], e = offsets[node + 1];
    int i = b;
    for (; i + 7 < e; i += 8) {
        int s0 = csr_src[i],     s1 = csr_src[i + 1], s2 = csr_src[i + 2], s3 = csr_src[i + 3];
        int s4 = csr_src[i + 4], s5 = csr_src[i + 5], s6 = csr_src[i + 6], s7 = csr_src[i + 7];
        unsigned int v0 = base[(size_t)s0 * 64 + lane];
        unsigned int v1 = base[(size_t)s1 * 64 + lane];
        unsigned int v2 = base[(size_t)s2 * 64 + lane];
        unsigned int v3 = base[(size_t)s3 * 64 + lane];
        unsigned int v4 = base[(size_t)s4 * 64 + lane];
        unsigned int v5 = base[(size_t)s5 * 64 + lane];
        unsigned int v6 = base[(size_t)s6 * 64 + lane];
        unsigned int v7 = base[(size_t)s7 * 64 + lane];
        ax += bflo(v0) + bflo(v1) + bflo(v2) + bflo(v3)
            + bflo(v4) + bflo(v5) + bflo(v6) + bflo(v7);
        ay += bfhi(v0) + bfhi(v1) + bfhi(v2) + bfhi(v3)
            + bfhi(v4) + bfhi(v5) + bfhi(v6) + bfhi(v7);
    }
    for (; i + 3 < e; i += 4) {
        int s0 = csr_src[i], s1 = csr_src[i + 1], s2 = csr_src[i + 2], s3 = csr_src[i + 3];
        unsigned int v0 = base[(size_t)s0 * 64 + lane];
        unsigned int v1 = base[(size_t)s1 * 64 + lane];
        unsigned int v2 = base[(size_t)s2 * 64 + lane];
        unsigned int v3 = base[(size_t)s3 * 64 + lane];
        ax += bflo(v0) + bflo(v1) + bflo(v2) + bflo(v3);
        ay += bfhi(v0) + bfhi(v1) + bfhi(v2) + bfhi(v3);
    }
    for (; i < e; ++i) {
        unsigned int v = base[(size_t)csr_src[i] * 64 + lane];
        ax += bflo(v); ay += bfhi(v);
    }
    ((unsigned int*)hb)[(size_t)node * 64 + lane] = packbf(ax, ay);
}

// ---------------- fused layer: out = relu(relu(BN(in@W1))@W2 + b2) ----------------
__global__ __launch_bounds__(512) void fused_gemm(const ushort* __restrict__ in,
                                                  ushort* __restrict__ out,
                                                  const ushort* __restrict__ Wt1,
                                                  const ushort* __restrict__ Wt2,
                                                  const float* __restrict__ fold1,
                                                  const float* __restrict__ fold2) {
    __shared__ ushort As[128 * 136];    // A tile, then H tile
    __shared__ ushort Bs1[128 * 136];   // W1^T, then C staging
    __shared__ ushort Bs2[128 * 136];   // W2^T
    ushort* Cs = Bs1;
    int t = threadIdx.x;
    int row0 = blockIdx.x * 128;        // 782 blocks, last partial (32 rows)

#pragma unroll
    for (int i = 0; i < 4; ++i) {
        int f = t + 512 * i; int m = f >> 4, g = f & 15;
        *(float4*)(As + m * 136 + g * 8) = *(const float4*)(in + (size_t)(row0 + m) * D + g * 8);
        *(float4*)(Bs1 + m * 136 + g * 8) = *(const float4*)(Wt1 + (size_t)m * D + g * 8);
        *(float4*)(Bs2 + m * 136 + g * 8) = *(const float4*)(Wt2 + (size_t)m * D + g * 8);
    }
    __syncthreads();

    int lane = t & 63, wv = t >> 6;
    int quad = lane >> 4, mr = lane & 15;
    int mbase = wv * 16;
    const ushort* ap = As + (mbase + mr) * 136 + quad * 8;
    bf16x8 a0 = *(const bf16x8*)(ap);
    bf16x8 a1 = *(const bf16x8*)(ap + 32);
    bf16x8 a2 = *(const bf16x8*)(ap + 64);
    bf16x8 a3 = *(const bf16x8*)(ap + 96);
    __syncthreads();                    // all waves hold A-frags; As reusable for H

#pragma unroll
    for (int nt = 0; nt < 8; ++nt) {
        const ushort* bq = Bs1 + (nt * 16 + mr) * 136 + quad * 8;
        bf16x8 b0 = *(const bf16x8*)(bq);
        bf16x8 b1 = *(const bf16x8*)(bq + 32);
        bf16x8 b2 = *(const bf16x8*)(bq + 64);
        bf16x8 b3 = *(const bf16x8*)(bq + 96);
        f32x4 acc = {0.f, 0.f, 0.f, 0.f};
        acc = __builtin_amdgcn_mfma_f32_16x16x32_bf16(a0, b0, acc, 0, 0, 0);
        acc = __builtin_amdgcn_mfma_f32_16x16x32_bf16(a1, b1, acc, 0, 0, 0);
        acc = __builtin_amdgcn_mfma_f32_16x16x32_bf16(a2, b2, acc, 0, 0, 0);
        acc = __builtin_amdgcn_mfma_f32_16x16x32_bf16(a3, b3, acc, 0, 0, 0);
        int j = nt * 16 + mr;           // C/D: col=lane&15, row=quad*4+reg (m89)
        float s = fold1[j], o = fold1[D + j];
#pragma unroll
        for (int r = 0; r < 4; ++r) {
            float z = fmaxf(fmaf(acc[r], s, o), 0.0f);
            As[(mbase + quad * 4 + r) * 136 + j] = f2bf(z);
        }
    }
    __syncthreads();                    // gemm1 done everywhere -> Bs1 free (Cs)

    const ushort* hp = As + (mbase + mr) * 136 + quad * 8;
    bf16x8 h0 = *(const bf16x8*)(hp);
    bf16x8 h1 = *(const bf16x8*)(hp + 32);
    bf16x8 h2 = *(const bf16x8*)(hp + 64);
    bf16x8 h3 = *(const bf16x8*)(hp + 96);
#pragma unroll
    for (int nt = 0; nt < 8; ++nt) {
        const ushort* bq = Bs2 + (nt * 16 + mr) * 136 + quad * 8;
        bf16x8 b0 = *(const bf16x8*)(bq);
        bf16x8 b1 = *(const bf16x8*)(bq + 32);
        bf16x8 b2 = *(const bf16x8*)(bq + 64);
        bf16x8 b3 = *(const bf16x8*)(bq + 96);
        f32x4 acc = {0.f, 0.f, 0.f, 0.f};
        acc = __builtin_amdgcn_mfma_f32_16x16x32_bf16(h0, b0, acc, 0, 0, 0);
        acc = __builtin_amdgcn_mfma_f32_16x16x32_bf16(h1, b1, acc, 0, 0, 0);
        acc = __builtin_amdgcn_mfma_f32_16x16x32_bf16(h2, b2, acc, 0, 0, 0);
        acc = __builtin_amdgcn_mfma_f32_16x16x32_bf16(h3, b3, acc, 0, 0, 0);
        int j = nt * 16 + mr;
        float o = fold2[D + j];
#pragma unroll
        for (int r = 0; r < 4; ++r) {
            float z = fmaxf(acc[r] + o, 0.0f);
            Cs[(mbase + quad * 4 + r) * 136 + j] = f2bf(z);
        }
    }
    __syncthreads();

#pragma unroll
    for (int i = 0; i < 8; ++i) {       // coalesced copy-out, float2 = 4 bf16
        int f = t + 512 * i; int lr = f >> 5, g = f & 31;
        if (row0 + lr < N_NODES)
            *(float2*)(out + (size_t)(row0 + lr) * D + g * 4) =
                *(const float2*)(Cs + lr * 136 + g * 4);
    }
}

// ---------------- pooling (bf16 in, fp32 out) ----------------
__global__ __launch_bounds__(128) void pool_kernel(const ushort* __restrict__ xb,
                                                   const int* __restrict__ gstart,
                                                   float* __restrict__ g) {
    int gr = blockIdx.x, j = threadIdx.x;
    float acc = 0.0f;
    int b = gstart[gr], e = gstart[gr + 1];
    for (int i = b; i < e; ++i)
        acc += __uint_as_float(((unsigned int)xb[(size_t)i * D + j]) << 16);
    g[gr * D + j] = acc;
}

// ---------------- head (fp32) ----------------
__global__ __launch_bounds__(128) void head_kernel(const float* __restrict__ g,
                                                   const float* __restrict__ W1,
                                                   const float* __restrict__ b1,
                                                   const float* __restrict__ W2,
                                                   const float* __restrict__ b2,
                                                   float* __restrict__ out) {
    __shared__ float row[128];
    __shared__ float t1[128];
    int r = blockIdx.x, j = threadIdx.x;
    row[j] = g[r * D + j];
    __syncthreads();
    float acc = b1[j];
    for (int k = 0; k < D; ++k) acc = fmaf(row[k], W1[k * D + j], acc);
    t1[j] = fmaxf(acc, 0.0f);
    __syncthreads();
    float acc2 = b2[j];
    for (int k = 0; k < D; ++k) acc2 = fmaf(t1[k], W2[k * D + j], acc2);
    out[r * D + j] = acc2;
}

// ---------------- launcher ----------------
extern "C" void kernel_launch(void* const* d_in, const int* in_sizes, int n_in,
                              void* d_out, int out_size, void* d_ws, size_t ws_size,
                              hipStream_t stream) {
    const float* x        = (const float*)d_in[0];
    const int*   ei       = (const int*)d_in[1];
    const int*   src      = ei;
    const int*   dst      = ei + N_EDGES;
    const int*   batch    = (const int*)d_in[2];
    const float* conv_W1  = (const float*)d_in[3];
    const float* conv_b1  = (const float*)d_in[4];
    const float* bn_gamma = (const float*)d_in[5];
    const float* bn_beta  = (const float*)d_in[6];
    const float* bn_mean  = (const float*)d_in[7];
    const float* bn_var   = (const float*)d_in[8];
    const float* conv_W2  = (const float*)d_in[9];
    const float* conv_b2  = (const float*)d_in[10];
    const float* head_W1  = (const float*)d_in[11];
    const float* head_b1  = (const float*)d_in[12];
    const float* head_W2  = (const float*)d_in[13];
    const float* head_b2  = (const float*)d_in[14];
    float* out = (float*)d_out;

    char* ws = (char*)d_ws;
    size_t off = 0;
    auto alloc = [&](size_t bytes) -> void* {
        void* p = ws + off;
        off = (off + bytes + 255) & ~(size_t)255;
        return p;
    };
    const size_t NODE_BUF = (size_t)(N_NODES + 128) * D * sizeof(ushort);
    ushort* buf0    = (ushort*)alloc(NODE_BUF);
    ushort* buf1    = (ushort*)alloc(NODE_BUF);
    ushort* Wt      = (ushort*)alloc((size_t)6 * D * D * sizeof(ushort));
    float*  folds   = (float*)alloc((size_t)6 * 2 * D * sizeof(float));
    unsigned int* squeue = (unsigned int*)alloc((size_t)FNSLICE * FSLICE_CAP * sizeof(unsigned int));
    int*   csr_src  = (int*)alloc((size_t)N_EDGES * sizeof(int));
    int*   offsets  = (int*)alloc((size_t)(N_NODES + 1) * sizeof(int));
    int*   slice_tail = (int*)alloc((size_t)FNSLICE * sizeof(int));
    int*   slice_base = (int*)alloc((size_t)FNSLICE * sizeof(int));
    int*   gstart   = (int*)alloc((size_t)(N_GRAPHS + 1) * sizeof(int));
    float* gpool    = (float*)alloc((size_t)N_GRAPHS * D * sizeof(float));

    zero_kernel<<<1, 128, 0, stream>>>(slice_tail, FNSLICE);
    compact_kernel<<<CGRID, 256, 0, stream>>>(src, dst, squeue, slice_tail);
    slice_scan<<<1, 128, 0, stream>>>(slice_tail, slice_base, offsets);
    fill_local<<<FNSLICE, 1024, 0, stream>>>(squeue, slice_tail, slice_base,
                                             offsets, csr_src);
    gstart_kernel<<<(N_GRAPHS + 1 + 255) / 256, 256, 0, stream>>>(batch, gstart);
    cvt_x_kernel<<<(N_NODES * D) / (256 * 8), 256, 0, stream>>>(x, buf0);
    prep_w_kernel<<<dim3(128, 6), 128, 0, stream>>>(conv_W1, conv_W2, Wt);
    prep_fold_kernel<<<6, 128, 0, stream>>>(conv_b1, bn_gamma, bn_beta,
                                            bn_mean, bn_var, conv_b2, folds);

    const int FUSED_GRID = (N_NODES + 127) / 128;   // 782
    for (int l = 0; l < 3; ++l) {
        gather_bf16<<<N_NODES / 4, 256, 0, stream>>>(buf0, offsets, csr_src, buf1);
        fused_gemm<<<FUSED_GRID, 512, 0, stream>>>(buf1, buf0,
            Wt + (size_t)(2 * l) * D * D, Wt + (size_t)(2 * l + 1) * D * D,
            folds + (size_t)(2 * l) * 2 * D, folds + (size_t)(2 * l + 1) * 2 * D);
    }

    pool_kernel<<<N_GRAPHS, 128, 0, stream>>>(buf0, gstart, gpool);
    head_kernel<<<N_GRAPHS, 128, 0, stream>>>(gpool, head_W1, head_b1,
                                              head_W2, head_b2, out);
}